// Round 7
// baseline (2003.043 us; speedup 1.0000x reference)
//
#include <hip/hip_runtime.h>

#define NN 100000
#define NE 1600000
#define NCLS 101
#define EPS_BN 1e-5f
#define NINF (-__builtin_inff())
#define NBUCK 196      // ceil(NN/512)
#define BCAP 12288     // max edges/bucket (mean 8192, sd ~90)

__device__ __forceinline__ int rl_i(int v, int j) {
    return __builtin_amdgcn_readlane(v, j);
}
__device__ __forceinline__ float rl_f(float v, int j) {
    return __int_as_float(__builtin_amdgcn_readlane(__float_as_int(v), j));
}

// ============================================================================
// CSR build, bucketed: bucket append -> bucket scan -> per-bucket LDS sort
// ============================================================================
// bcnt16: one counter per 64B line -> atomic ops spread over 196 L2 lines.
__global__ __launch_bounds__(256) void bucket_k(const int* __restrict__ src,
                                                const int* __restrict__ dst,
                                                int* __restrict__ bcnt16,
                                                int* __restrict__ bstore) {
    int e = blockIdx.x * 256 + threadIdx.x;
    if (e >= NE) return;
    int d = dst[e], s = src[e];
    int b = d >> 9;
    int p = atomicAdd(&bcnt16[b * 16], 1);
    if (p < BCAP) bstore[(size_t)b * BCAP + p] = ((d & 511) << 17) | s;
}

__global__ __launch_bounds__(256) void bscan_k(const int* __restrict__ bcnt16,
                                               int* __restrict__ bbase) {
    __shared__ int sh[256];
    int t = threadIdx.x;
    int v = (t < NBUCK) ? bcnt16[t * 16] : 0;
    sh[t] = v;
    __syncthreads();
    for (int off = 1; off < 256; off <<= 1) {
        int u = (t >= off) ? sh[t - off] : 0;
        __syncthreads();
        sh[t] += u;
        __syncthreads();
    }
    if (t < NBUCK) bbase[t] = sh[t] - v;   // exclusive
}

// one block per bucket: hist 512 local nodes -> scan -> rs + ordered csrc
__global__ __launch_bounds__(512) void b2csr_k(const int* __restrict__ bcnt16,
                                               const int* __restrict__ bbase,
                                               const int* __restrict__ bstore,
                                               int* __restrict__ rs,
                                               int* __restrict__ csrc) {
    __shared__ int hist[512];
    __shared__ int scn[512];
    __shared__ int cur[512];
    int b = blockIdx.x;
    int t = threadIdx.x;
    int cnt = bcnt16[b * 16];
    if (cnt > BCAP) cnt = BCAP;
    int gbase = bbase[b];
    const int* bs = bstore + (size_t)b * BCAP;
    hist[t] = 0;
    __syncthreads();
    for (int i = t; i < cnt; i += 512) atomicAdd(&hist[bs[i] >> 17], 1);
    __syncthreads();
    int v = hist[t];
    scn[t] = v;
    __syncthreads();
    for (int off = 1; off < 512; off <<= 1) {
        int u = (t >= off) ? scn[t - off] : 0;
        __syncthreads();
        scn[t] += u;
        __syncthreads();
    }
    int ex = scn[t] - v;
    cur[t] = ex;
    int node = b * 512 + t;
    if (node < NN) rs[node] = gbase + ex;
    if (b == 0 && t == 0) rs[NN] = NE;
    __syncthreads();
    for (int i = t; i < cnt; i += 512) {
        int e = bs[i];
        int p = atomicAdd(&cur[e >> 17], 1);
        csrc[gbase + p] = e & 0x1FFFF;
    }
}

__global__ __launch_bounds__(256) void pos2_k(const float* __restrict__ pos,
                                              float2* __restrict__ pos2) {
    int n = blockIdx.x * 256 + threadIdx.x;
    if (n < NN) pos2[n] = make_float2(pos[n * 3], pos[n * 3 + 1]);
}

// ============================================================================
// One-shot weight packing: transpose every GEMM weight into padded [K][CP].
// ============================================================================
__global__ __launch_bounds__(256) void pack_all_k(
    const float* __restrict__ wl_stem, const float* __restrict__ wg_stem,
    const float* __restrict__ wl_c1, const float* __restrict__ bl_c1,
    const float* __restrict__ wl_c2, const float* __restrict__ bl_c2,
    const float* __restrict__ wg_c1, const float* __restrict__ wg_c2,
    const float* __restrict__ wl_reg, const float* __restrict__ wl_obj,
    const float* __restrict__ bl_reg, const float* __restrict__ bl_obj,
    const float* __restrict__ wl_cls, const float* __restrict__ wg_cls,
    float* __restrict__ wT_sp, float* __restrict__ wT_sg,
    float* __restrict__ wT_12, float* __restrict__ wT_g1,
    float* __restrict__ wT_g2, float* __restrict__ wT_ro,
    float* __restrict__ wT_cp, float* __restrict__ wT_cg,
    float* __restrict__ bAB, float* __restrict__ wro, float* __restrict__ bro) {
    int u = blockIdx.x * 256 + threadIdx.x;
    if (u < 4096) { int j = u >> 6, c = u & 63; wT_sp[u] = wl_stem[c * 66 + j]; return; }
    u -= 4096;
    if (u < 4096) { int j = u >> 6, c = u & 63; wT_sg[u] = wg_stem[c * 64 + j]; return; }
    u -= 4096;
    if (u < 8192) { int j = u >> 7, c = u & 127; int k = c >> 1;
        wT_12[u] = ((c & 1) ? wl_c2 : wl_c1)[k * 66 + j]; return; }
    u -= 8192;
    if (u < 4096) { int j = u >> 6, c = u & 63; wT_g1[u] = wg_c1[c * 64 + j]; return; }
    u -= 4096;
    if (u < 4096) { int j = u >> 6, c = u & 63; wT_g2[u] = wg_c2[c * 64 + j]; return; }
    u -= 4096;
    if (u < 1024) { int j = u >> 4, c = u & 15;
        wT_ro[u] = (c < 4) ? wl_reg[c * 66 + j] : ((c == 4) ? wl_obj[j] : 0.f); return; }
    u -= 1024;
    if (u < 7168) { int j = u / 112, c = u - j * 112;
        wT_cp[u] = (c < NCLS) ? wl_cls[c * 66 + j] : 0.f; return; }
    u -= 7168;
    if (u < 11312) { int j = u / 112, c = u - j * 112;
        wT_cg[u] = (c < NCLS) ? wg_cls[c * NCLS + j] : 0.f; return; }
    u -= 11312;
    if (u < 128) { bAB[u] = (u & 1) ? bl_c2[u >> 1] : bl_c1[u >> 1]; return; }
    u -= 128;
    if (u < 330) { int cc = u / 66, j = u - cc * 66;
        wro[u] = (cc < 4) ? wl_reg[u] : wl_obj[j]; return; }
    u -= 330;
    if (u < 5) bro[u] = (u < 4) ? bl_reg[u] : bl_obj[0];
}

// ============================================================================
// Node-side GEMM: out[n][c] = sum_j xs(n,j)*wT[j][c] + b[c]
// wT pre-transposed [K][CP]; staging = coalesced float4 copy. x-tile
// transposed in LDS [j][n] (odd stride). BNF: fused BN+ReLU on input.
// STOUT: fused per-channel sum/sumsq (shuffle butterfly + 2 atomics/wave).
// ============================================================================
template <int COUT, int CPW, int K, int IS, int OS, int MT, bool BNF, bool STOUT>
__global__ __launch_bounds__(256) void gemm_k(const float* __restrict__ in,
                                              const float* __restrict__ wT,
                                              const float* __restrict__ bias,
                                              const float* __restrict__ st,
                                              float* __restrict__ stout,
                                              float* __restrict__ out) {
    constexpr int CP = 4 * CPW;
    constexpr int RM = MT / 64;
    constexpr int XR = MT + 1;
    __shared__ __align__(16) float xs[K * XR];
    __shared__ __align__(16) float wsh[K * CP];
    int base = blockIdx.x * MT;
    for (int p = threadIdx.x; p < K * CP / 4; p += 256)
        ((float4*)wsh)[p] = ((const float4*)wT)[p];
    for (int p = threadIdx.x; p < MT * K; p += 256) {
        int n = p / K, j = p - n * K;
        float v = (base + n < NN) ? in[(size_t)(base + n) * IS + j] : 0.f;
        if constexpr (BNF) v = fmaxf(fmaf(v, st[128 + j], st[192 + j]), 0.f);
        xs[j * XR + n] = v;
    }
    __syncthreads();
    int wid = __builtin_amdgcn_readfirstlane(threadIdx.x >> 6);
    int lane = threadIdx.x & 63;
    int c0 = wid * CPW;
    if (c0 >= COUT) return;     // after the only barrier -> safe
    float acc[RM][CPW];
#pragma unroll
    for (int k = 0; k < CPW; ++k) {
        float bv = (c0 + k < COUT) ? bias[c0 + k] : 0.f;
#pragma unroll
        for (int r = 0; r < RM; ++r) acc[r][k] = bv;
    }
    for (int j = 0; j < K; ++j) {
        float a[RM];
#pragma unroll
        for (int r = 0; r < RM; ++r) a[r] = xs[j * XR + 64 * r + lane];
#pragma unroll
        for (int q = 0; q < CPW / 4; ++q) {
            float4 wv = *(const float4*)&wsh[j * CP + c0 + 4 * q];
#pragma unroll
            for (int r = 0; r < RM; ++r) {
                acc[r][4 * q + 0] = fmaf(a[r], wv.x, acc[r][4 * q + 0]);
                acc[r][4 * q + 1] = fmaf(a[r], wv.y, acc[r][4 * q + 1]);
                acc[r][4 * q + 2] = fmaf(a[r], wv.z, acc[r][4 * q + 2]);
                acc[r][4 * q + 3] = fmaf(a[r], wv.w, acc[r][4 * q + 3]);
            }
        }
    }
#pragma unroll
    for (int r = 0; r < RM; ++r) {
        int node = base + 64 * r + lane;
        if (node < NN) {
#pragma unroll
            for (int k = 0; k < CPW; ++k)
                if (c0 + k < COUT) out[(size_t)node * OS + c0 + k] = acc[r][k];
        }
    }
    if constexpr (STOUT) {
#pragma unroll
        for (int k = 0; k < CPW; ++k) {
            if (c0 + k < COUT) {
                float s = 0.f, q = 0.f;
#pragma unroll
                for (int r = 0; r < RM; ++r) {
                    float v = (base + 64 * r + lane < NN) ? acc[r][k] : 0.f;
                    s += v;
                    q = fmaf(v, v, q);
                }
#pragma unroll
                for (int off = 1; off < 64; off <<= 1) {
                    s += __shfl_xor(s, off, 64);
                    q += __shfl_xor(q, off, 64);
                }
                if (lane == 0) {
                    atomicAdd(&stout[c0 + k], s);
                    atomicAdd(&stout[64 + c0 + k], q);
                }
            }
        }
    }
}

// ============================================================================
// Edge segment-max over CSR. Wave per node, lane = channel. 64-edge batches:
// indices+pos2 loaded coalesced once, broadcast via readlane; 8 gathers in
// flight per unrolled chunk (MLP).
// ============================================================================
__global__ __launch_bounds__(256) void edge1_k(const float* __restrict__ y,   // stride 64
                                               const float2* __restrict__ pos2,
                                               const int* __restrict__ rs,
                                               const int* __restrict__ csrc,
                                               const float* __restrict__ wl,  // (64,66)
                                               float* __restrict__ agg) {
    int wid = __builtin_amdgcn_readfirstlane(threadIdx.x >> 6);
    int lane = threadIdx.x & 63;
    int node = blockIdx.x * 4 + wid;
    if (node >= NN) return;
    float wp0 = wl[lane * 66 + 64], wp1 = wl[lane * 66 + 65];
    float2 pd = pos2[node];
    int i0 = rs[node], i1 = rs[node + 1];
    float acc = NINF;
    for (int ib = i0; ib < i1; ib += 64) {
        int m = i1 - ib;
        if (m > 64) m = 64;
        int t = ib + lane;
        int idx = (t < i1) ? csrc[t] : 0;
        float2 pp = pos2[idx];
        float ppx = pp.x, ppy = pp.y;
        int j = 0;
        for (; j + 8 <= m; j += 8) {
            float v[8];
#pragma unroll
            for (int q = 0; q < 8; ++q)
                v[q] = y[(size_t)rl_i(idx, j + q) * 64 + lane];
#pragma unroll
            for (int q = 0; q < 8; ++q) {
                float dx = rl_f(ppx, j + q) - pd.x, dy = rl_f(ppy, j + q) - pd.y;
                acc = fmaxf(acc, fmaf(dy, wp1, fmaf(dx, wp0, v[q])));
            }
        }
        for (; j + 4 <= m; j += 4) {
            float v[4];
#pragma unroll
            for (int q = 0; q < 4; ++q)
                v[q] = y[(size_t)rl_i(idx, j + q) * 64 + lane];
#pragma unroll
            for (int q = 0; q < 4; ++q) {
                float dx = rl_f(ppx, j + q) - pd.x, dy = rl_f(ppy, j + q) - pd.y;
                acc = fmaxf(acc, fmaf(dy, wp1, fmaf(dx, wp0, v[q])));
            }
        }
        for (; j < m; ++j) {
            int s = rl_i(idx, j);
            float v = y[(size_t)s * 64 + lane];
            acc = fmaxf(acc, fmaf(rl_f(ppy, j) - pd.y, wp1,
                                  fmaf(rl_f(ppx, j) - pd.x, wp0, v)));
        }
    }
    agg[(size_t)node * 64 + lane] = fmaxf(acc, 0.0f);
}

// y12 layout: [n][64]{float2} = (c1 proj, c2 proj)
__global__ __launch_bounds__(256) void edge2_k(const float2* __restrict__ y12,
                                               const float2* __restrict__ pos2,
                                               const int* __restrict__ rs,
                                               const int* __restrict__ csrc,
                                               const float* __restrict__ wlA,
                                               const float* __restrict__ wlB,
                                               float* __restrict__ a1,
                                               float* __restrict__ a2) {
    int wid = __builtin_amdgcn_readfirstlane(threadIdx.x >> 6);
    int lane = threadIdx.x & 63;
    int node = blockIdx.x * 4 + wid;
    if (node >= NN) return;
    float wa0 = wlA[lane * 66 + 64], wa1 = wlA[lane * 66 + 65];
    float wb0 = wlB[lane * 66 + 64], wb1 = wlB[lane * 66 + 65];
    float2 pd = pos2[node];
    int i0 = rs[node], i1 = rs[node + 1];
    float accA = NINF, accB = NINF;
    for (int ib = i0; ib < i1; ib += 64) {
        int m = i1 - ib;
        if (m > 64) m = 64;
        int t = ib + lane;
        int idx = (t < i1) ? csrc[t] : 0;
        float2 pp = pos2[idx];
        float ppx = pp.x, ppy = pp.y;
        int j = 0;
        for (; j + 8 <= m; j += 8) {
            float2 v[8];
#pragma unroll
            for (int q = 0; q < 8; ++q)
                v[q] = y12[(size_t)rl_i(idx, j + q) * 64 + lane];
#pragma unroll
            for (int q = 0; q < 8; ++q) {
                float dx = rl_f(ppx, j + q) - pd.x, dy = rl_f(ppy, j + q) - pd.y;
                accA = fmaxf(accA, fmaf(dy, wa1, fmaf(dx, wa0, v[q].x)));
                accB = fmaxf(accB, fmaf(dy, wb1, fmaf(dx, wb0, v[q].y)));
            }
        }
        for (; j + 4 <= m; j += 4) {
            float2 v[4];
#pragma unroll
            for (int q = 0; q < 4; ++q)
                v[q] = y12[(size_t)rl_i(idx, j + q) * 64 + lane];
#pragma unroll
            for (int q = 0; q < 4; ++q) {
                float dx = rl_f(ppx, j + q) - pd.x, dy = rl_f(ppy, j + q) - pd.y;
                accA = fmaxf(accA, fmaf(dy, wa1, fmaf(dx, wa0, v[q].x)));
                accB = fmaxf(accB, fmaf(dy, wb1, fmaf(dx, wb0, v[q].y)));
            }
        }
        for (; j < m; ++j) {
            float2 v = y12[(size_t)rl_i(idx, j) * 64 + lane];
            float dx = rl_f(ppx, j) - pd.x, dy = rl_f(ppy, j) - pd.y;
            accA = fmaxf(accA, fmaf(dy, wa1, fmaf(dx, wa0, v.x)));
            accB = fmaxf(accB, fmaf(dy, wb1, fmaf(dx, wb0, v.y)));
        }
    }
    a1[(size_t)node * 64 + lane] = fmaxf(accA, 0.0f);
    a2[(size_t)node * 64 + lane] = fmaxf(accB, 0.0f);
}

// cls: wave per node, lane covers channels {lane, lane+64 (clamped)}
__global__ __launch_bounds__(256) void edge_cls_k(const float* __restrict__ y,  // stride 104
                                                  const float2* __restrict__ pos2,
                                                  const int* __restrict__ rs,
                                                  const int* __restrict__ csrc,
                                                  const float* __restrict__ wl,  // (101,66)
                                                  float* __restrict__ agg) {     // stride 104
    int wid = __builtin_amdgcn_readfirstlane(threadIdx.x >> 6);
    int lane = threadIdx.x & 63;
    int node = blockIdx.x * 4 + wid;
    if (node >= NN) return;
    int chi = (lane + 64 < NCLS) ? (lane + 64) : (NCLS - 1);
    float wa0 = wl[lane * 66 + 64], wa1 = wl[lane * 66 + 65];
    float wb0 = wl[chi * 66 + 64], wb1 = wl[chi * 66 + 65];
    float2 pd = pos2[node];
    int i0 = rs[node], i1 = rs[node + 1];
    float accA = NINF, accB = NINF;
    for (int ib = i0; ib < i1; ib += 64) {
        int m = i1 - ib;
        if (m > 64) m = 64;
        int t = ib + lane;
        int idx = (t < i1) ? csrc[t] : 0;
        float2 pp = pos2[idx];
        float ppx = pp.x, ppy = pp.y;
        int j = 0;
        for (; j + 4 <= m; j += 4) {
            float va[4], vb[4];
#pragma unroll
            for (int q = 0; q < 4; ++q) {
                size_t row = (size_t)rl_i(idx, j + q) * 104;
                va[q] = y[row + lane];
                vb[q] = y[row + chi];
            }
#pragma unroll
            for (int q = 0; q < 4; ++q) {
                float dx = rl_f(ppx, j + q) - pd.x, dy = rl_f(ppy, j + q) - pd.y;
                accA = fmaxf(accA, fmaf(dy, wa1, fmaf(dx, wa0, va[q])));
                accB = fmaxf(accB, fmaf(dy, wb1, fmaf(dx, wb0, vb[q])));
            }
        }
        for (; j < m; ++j) {
            size_t row = (size_t)rl_i(idx, j) * 104;
            float va = y[row + lane];
            float vb = y[row + chi];
            float dx = rl_f(ppx, j) - pd.x, dy = rl_f(ppy, j) - pd.y;
            accA = fmaxf(accA, fmaf(dy, wa1, fmaf(dx, wa0, va)));
            accB = fmaxf(accB, fmaf(dy, wb1, fmaf(dx, wb0, vb)));
        }
    }
    agg[(size_t)node * 104 + lane] = fmaxf(accA, 0.0f);
    if (lane + 64 < NCLS) agg[(size_t)node * 104 + 64 + lane] = fmaxf(accB, 0.0f);
}

// reg+obj: 5 channels packed stride 8; wave = 8 edge-slots x 8 channel-slots
__global__ __launch_bounds__(256) void edge_ro_k(const float* __restrict__ y,  // stride 8
                                                 const float2* __restrict__ pos2,
                                                 const int* __restrict__ rs,
                                                 const int* __restrict__ csrc,
                                                 const float* __restrict__ wro,  // (5,66)
                                                 float* __restrict__ aggr,
                                                 float* __restrict__ aggo) {
    int wid = __builtin_amdgcn_readfirstlane(threadIdx.x >> 6);
    int lane = threadIdx.x & 63;
    int node = blockIdx.x * 4 + wid;
    if (node >= NN) return;
    int k = lane >> 3, c = lane & 7;
    int cc = (c < 5) ? c : 4;
    float wp0 = wro[cc * 66 + 64], wp1 = wro[cc * 66 + 65];
    float2 pd = pos2[node];
    int i0 = rs[node], i1 = rs[node + 1];
    float acc = NINF;
    for (int i = i0 + k; i < i1; i += 8) {
        int s = csrc[i];
        float2 p = pos2[s];
        float v = y[(size_t)s * 8 + cc];
        acc = fmaxf(acc, fmaf(p.y - pd.y, wp1, fmaf(p.x - pd.x, wp0, v)));
    }
    acc = fmaxf(acc, __shfl_xor(acc, 8, 64));
    acc = fmaxf(acc, __shfl_xor(acc, 16, 64));
    acc = fmaxf(acc, __shfl_xor(acc, 32, 64));
    acc = fmaxf(acc, 0.0f);
    if (lane < 5) {
        if (lane < 4) aggr[(size_t)node * 4 + lane] = acc;
        else          aggo[node] = acc;
    }
}

__global__ void bnpar_k(float* __restrict__ st, const float* __restrict__ g,
                        const float* __restrict__ b) {
    int c = threadIdx.x;
    if (c >= 64) return;
    float mu = st[c] * (1.0f / NN);
    float var = st[64 + c] * (1.0f / NN) - mu * mu;
    float sc = g[c] * rsqrtf(var + EPS_BN);
    st[128 + c] = sc;
    st[192 + c] = b[c] - mu * sc;
}

__global__ __launch_bounds__(256) void final_ro_k(const float* __restrict__ aggr,
                                                  const float* __restrict__ aggo,
                                                  const float* __restrict__ wgr,
                                                  const float* __restrict__ bgr,
                                                  const float* __restrict__ wgo,
                                                  const float* __restrict__ bgo,
                                                  float* __restrict__ out) {
    int n = blockIdx.x * 256 + threadIdx.x;
    if (n >= NN) return;
    float a0 = aggr[(size_t)n * 4 + 0], a1 = aggr[(size_t)n * 4 + 1];
    float a2 = aggr[(size_t)n * 4 + 2], a3 = aggr[(size_t)n * 4 + 3];
    float* reg = out + (size_t)NN * NCLS;
    float* obj = reg + (size_t)NN * 4;
#pragma unroll
    for (int k = 0; k < 4; ++k) {
        float acc = bgr[k];
        acc = fmaf(a0, wgr[k * 4 + 0], acc);
        acc = fmaf(a1, wgr[k * 4 + 1], acc);
        acc = fmaf(a2, wgr[k * 4 + 2], acc);
        acc = fmaf(a3, wgr[k * 4 + 3], acc);
        reg[(size_t)n * 4 + k] = acc;
    }
    obj[n] = fmaf(aggo[n], wgo[0], bgo[0]);
}

// ============================================================================
extern "C" void kernel_launch(void* const* d_in, const int* in_sizes, int n_in,
                              void* d_out, int out_size, void* d_ws, size_t ws_size,
                              hipStream_t stream) {
    const float* x   = (const float*)d_in[0];
    const float* pos = (const float*)d_in[1];
    const int* ei    = (const int*)d_in[2];
    const int* src = ei;
    const int* dst = ei + NE;
    const float* wl_stem = (const float*)d_in[3];
    const float* bl_stem = (const float*)d_in[4];
    const float* wg_stem = (const float*)d_in[5];
    const float* bg_stem = (const float*)d_in[6];
    const float* g_stem  = (const float*)d_in[7];
    const float* b_stem  = (const float*)d_in[8];
    const float* wl_c1 = (const float*)d_in[9];
    const float* bl_c1 = (const float*)d_in[10];
    const float* wg_c1 = (const float*)d_in[11];
    const float* bg_c1 = (const float*)d_in[12];
    const float* g_c1  = (const float*)d_in[13];
    const float* b_c1  = (const float*)d_in[14];
    const float* wl_c2 = (const float*)d_in[15];
    const float* bl_c2 = (const float*)d_in[16];
    const float* wg_c2 = (const float*)d_in[17];
    const float* bg_c2 = (const float*)d_in[18];
    const float* g_c2  = (const float*)d_in[19];
    const float* b_c2  = (const float*)d_in[20];
    const float* wl_reg = (const float*)d_in[21];
    const float* bl_reg = (const float*)d_in[22];
    const float* wg_reg = (const float*)d_in[23];
    const float* bg_reg = (const float*)d_in[24];
    const float* wl_cls = (const float*)d_in[25];
    const float* bl_cls = (const float*)d_in[26];
    const float* wg_cls = (const float*)d_in[27];
    const float* bg_cls = (const float*)d_in[28];
    const float* wl_obj = (const float*)d_in[29];
    const float* bl_obj = (const float*)d_in[30];
    const float* wg_obj = (const float*)d_in[31];
    const float* bg_obj = (const float*)d_in[32];

    float* ws = (float*)d_ws;
    // Arena: S0[N*128] | S1[N*64] | S2[N*64] | S3[N*64] | ints/smalls
    // bstore (9.6MB) aliases S0 (dead until y12 is written by the c1c2 gemm).
    float* S0 = ws;
    float* S1 = S0 + (size_t)NN * 128;
    float* S2 = S1 + (size_t)NN * 64;
    float* S3 = S2 + (size_t)NN * 64;
    float* y12   = S0;
    float* y_cls = S0;
    float* aggc  = S1;     // N*104 spans S1+S2 (both dead by then)
    int*   bstore = (int*)S0;                     // NBUCK*BCAP ints
    int*   rs   = (int*)(S3 + (size_t)NN * 64);   // NN+1 (padded to 100016)
    int*   csrc = rs + 100016;                    // NE
    float* pos2 = (float*)(csrc + NE);            // NN float2
    float* y_ro = pos2 + (size_t)NN * 2;          // NN*8
    float* aggr = y_ro + (size_t)NN * 8;          // NN*4
    float* aggo = aggr + (size_t)NN * 4;          // NN
    float* st   = aggo + NN;                      // 3*256
    float* st0 = st, *st1 = st + 256, *st2 = st + 512;
    float* wro = st + 768;                        // 336
    float* bro = wro + 336;                       // 8
    int*   bcnt16 = (int*)(bro + 8);              // NBUCK*16 (line-padded)
    int*   bbase  = bcnt16 + NBUCK * 16;          // 256
    float* wT_sp = (float*)(bbase + 256);         // [64][64]
    float* wT_sg = wT_sp + 4096;
    float* wT_12 = wT_sg + 4096;                  // [64][128]
    float* wT_g1 = wT_12 + 8192;
    float* wT_g2 = wT_g1 + 4096;
    float* wT_ro = wT_g2 + 4096;                  // [64][16]
    float* wT_cp = wT_ro + 1024;                  // [64][112]
    float* wT_cg = wT_cp + 7168;                  // [101][112]
    float* bAB   = wT_cg + 11312;                 // 128

    hipMemsetAsync(bcnt16, 0, NBUCK * 16 * sizeof(int), stream);
    hipMemsetAsync(st, 0, 768 * sizeof(float), stream);

    const int EB = (NE + 255) / 256;      // 6250
    const int NB = (NN + 255) / 256;      // 391
    const int N4 = (NN + 3) / 4;          // 25000
    const int G128 = (NN + 127) / 128;    // 782
    const int G64  = (NN + 63) / 64;      // 1563

    // ---- packing + CSR build + pos2 ----
    pack_all_k<<<175, 256, 0, stream>>>(wl_stem, wg_stem, wl_c1, bl_c1, wl_c2,
                                        bl_c2, wg_c1, wg_c2, wl_reg, wl_obj,
                                        bl_reg, bl_obj, wl_cls, wg_cls,
                                        wT_sp, wT_sg, wT_12, wT_g1, wT_g2,
                                        wT_ro, wT_cp, wT_cg, bAB, wro, bro);
    pos2_k<<<NB, 256, 0, stream>>>(pos, (float2*)pos2);
    bucket_k<<<EB, 256, 0, stream>>>(src, dst, bcnt16, bstore);
    bscan_k<<<1, 256, 0, stream>>>(bcnt16, bbase);
    b2csr_k<<<NBUCK, 512, 0, stream>>>(bcnt16, bbase, bstore, rs, csrc);

    // ---- stem ----
    gemm_k<64, 16, 64, 64, 64, 128, false, false><<<G128, 256, 0, stream>>>(
        x, wT_sp, bl_stem, nullptr, nullptr, S1);
    edge1_k<<<N4, 256, 0, stream>>>(S1, (float2*)pos2, rs, csrc, wl_stem, S2);
    gemm_k<64, 16, 64, 64, 64, 128, false, true><<<G128, 256, 0, stream>>>(
        S2, wT_sg, bg_stem, nullptr, st0, S2);
    bnpar_k<<<1, 64, 0, stream>>>(st0, g_stem, b_stem);

    // ---- c1 + c2 (BN fused into packed projection, shared edge pass) ----
    gemm_k<128, 32, 64, 64, 128, 128, true, false><<<G128, 256, 0, stream>>>(
        S2, wT_12, bAB, st0, nullptr, y12);
    edge2_k<<<N4, 256, 0, stream>>>((const float2*)y12, (float2*)pos2, rs, csrc,
                                    wl_c1, wl_c2, S1, S3);
    gemm_k<64, 16, 64, 64, 64, 128, false, true><<<G128, 256, 0, stream>>>(
        S1, wT_g1, bg_c1, nullptr, st1, S1);
    bnpar_k<<<1, 64, 0, stream>>>(st1, g_c1, b_c1);
    gemm_k<64, 16, 64, 64, 64, 128, false, true><<<G128, 256, 0, stream>>>(
        S3, wT_g2, bg_c2, nullptr, st2, S3);
    bnpar_k<<<1, 64, 0, stream>>>(st2, g_c2, b_c2);

    // ---- reg + obj heads (input x1 = BN(S1), fused) ----
    gemm_k<5, 4, 64, 64, 8, 128, true, false><<<G128, 256, 0, stream>>>(
        S1, wT_ro, bro, st1, nullptr, y_ro);
    edge_ro_k<<<N4, 256, 0, stream>>>(y_ro, (float2*)pos2, rs, csrc, wro, aggr, aggo);

    // ---- cls head (input x2 = BN(S3), fused) ----
    gemm_k<101, 28, 64, 64, 104, 128, true, false><<<G128, 256, 0, stream>>>(
        S3, wT_cp, bl_cls, st2, nullptr, y_cls);
    edge_cls_k<<<N4, 256, 0, stream>>>(y_cls, (float2*)pos2, rs, csrc, wl_cls, aggc);
    gemm_k<101, 28, 101, 104, 101, 64, false, false><<<G64, 256, 0, stream>>>(
        aggc, wT_cg, bg_cls, nullptr, nullptr, (float*)d_out);
    final_ro_k<<<NB, 256, 0, stream>>>(aggr, aggo, wg_reg, bg_reg, wg_obj, bg_obj,
                                       (float*)d_out);
}

// Round 8
// 1277.261 us; speedup vs baseline: 1.5682x; 1.5682x over previous
//
#include <hip/hip_runtime.h>

#define NN 100000
#define NE 1600000
#define NCLS 101
#define EPS_BN 1e-5f
#define NINF (-__builtin_inff())
#define NBUCK 196      // ceil(NN/512)
#define BCAP 12288     // max edges/bucket (mean 8192, sd ~90)
#define G128B 782      // ceil(NN/128) gemm blocks (stats partials stride)

__device__ __forceinline__ int rl_i(int v, int j) {
    return __builtin_amdgcn_readlane(v, j);
}
__device__ __forceinline__ float rl_f(float v, int j) {
    return __int_as_float(__builtin_amdgcn_readlane(__float_as_int(v), j));
}

// ============================================================================
// CSR build, bucketed: bucket append -> bucket scan -> per-bucket LDS sort
// ============================================================================
__global__ __launch_bounds__(256) void bucket_k(const int* __restrict__ src,
                                                const int* __restrict__ dst,
                                                int* __restrict__ bcnt16,
                                                int* __restrict__ bstore) {
    int e = blockIdx.x * 256 + threadIdx.x;
    if (e >= NE) return;
    int d = dst[e], s = src[e];
    int b = d >> 9;
    int p = atomicAdd(&bcnt16[b * 16], 1);
    if (p < BCAP) bstore[(size_t)b * BCAP + p] = ((d & 511) << 17) | s;
}

__global__ __launch_bounds__(256) void bscan_k(const int* __restrict__ bcnt16,
                                               int* __restrict__ bbase) {
    __shared__ int sh[256];
    int t = threadIdx.x;
    int v = (t < NBUCK) ? bcnt16[t * 16] : 0;
    sh[t] = v;
    __syncthreads();
    for (int off = 1; off < 256; off <<= 1) {
        int u = (t >= off) ? sh[t - off] : 0;
        __syncthreads();
        sh[t] += u;
        __syncthreads();
    }
    if (t < NBUCK) bbase[t] = sh[t] - v;   // exclusive
}

__global__ __launch_bounds__(512) void b2csr_k(const int* __restrict__ bcnt16,
                                               const int* __restrict__ bbase,
                                               const int* __restrict__ bstore,
                                               int* __restrict__ rs,
                                               int* __restrict__ csrc) {
    __shared__ int hist[512];
    __shared__ int scn[512];
    __shared__ int cur[512];
    int b = blockIdx.x;
    int t = threadIdx.x;
    int cnt = bcnt16[b * 16];
    if (cnt > BCAP) cnt = BCAP;
    int gbase = bbase[b];
    const int* bs = bstore + (size_t)b * BCAP;
    hist[t] = 0;
    __syncthreads();
    for (int i = t; i < cnt; i += 512) atomicAdd(&hist[bs[i] >> 17], 1);
    __syncthreads();
    int v = hist[t];
    scn[t] = v;
    __syncthreads();
    for (int off = 1; off < 512; off <<= 1) {
        int u = (t >= off) ? scn[t - off] : 0;
        __syncthreads();
        scn[t] += u;
        __syncthreads();
    }
    int ex = scn[t] - v;
    cur[t] = ex;
    int node = b * 512 + t;
    if (node < NN) rs[node] = gbase + ex;
    if (b == 0 && t == 0) rs[NN] = NE;
    __syncthreads();
    for (int i = t; i < cnt; i += 512) {
        int e = bs[i];
        int p = atomicAdd(&cur[e >> 17], 1);
        csrc[gbase + p] = e & 0x1FFFF;
    }
}

__global__ __launch_bounds__(256) void pos2_k(const float* __restrict__ pos,
                                              float2* __restrict__ pos2) {
    int n = blockIdx.x * 256 + threadIdx.x;
    if (n < NN) pos2[n] = make_float2(pos[n * 3], pos[n * 3 + 1]);
}

// ============================================================================
// One-shot weight packing: transpose every GEMM weight into padded [K][CP].
// ============================================================================
__global__ __launch_bounds__(256) void pack_all_k(
    const float* __restrict__ wl_stem, const float* __restrict__ wg_stem,
    const float* __restrict__ wl_c1, const float* __restrict__ bl_c1,
    const float* __restrict__ wl_c2, const float* __restrict__ bl_c2,
    const float* __restrict__ wg_c1, const float* __restrict__ wg_c2,
    const float* __restrict__ wl_reg, const float* __restrict__ wl_obj,
    const float* __restrict__ bl_reg, const float* __restrict__ bl_obj,
    const float* __restrict__ wl_cls, const float* __restrict__ wg_cls,
    float* __restrict__ wT_sp, float* __restrict__ wT_sg,
    float* __restrict__ wT_12, float* __restrict__ wT_g1,
    float* __restrict__ wT_g2, float* __restrict__ wT_ro,
    float* __restrict__ wT_cp, float* __restrict__ wT_cg,
    float* __restrict__ bAB, float* __restrict__ wro, float* __restrict__ bro) {
    int u = blockIdx.x * 256 + threadIdx.x;
    if (u < 4096) { int j = u >> 6, c = u & 63; wT_sp[u] = wl_stem[c * 66 + j]; return; }
    u -= 4096;
    if (u < 4096) { int j = u >> 6, c = u & 63; wT_sg[u] = wg_stem[c * 64 + j]; return; }
    u -= 4096;
    if (u < 8192) { int j = u >> 7, c = u & 127; int k = c >> 1;
        wT_12[u] = ((c & 1) ? wl_c2 : wl_c1)[k * 66 + j]; return; }
    u -= 8192;
    if (u < 4096) { int j = u >> 6, c = u & 63; wT_g1[u] = wg_c1[c * 64 + j]; return; }
    u -= 4096;
    if (u < 4096) { int j = u >> 6, c = u & 63; wT_g2[u] = wg_c2[c * 64 + j]; return; }
    u -= 4096;
    if (u < 1024) { int j = u >> 4, c = u & 15;
        wT_ro[u] = (c < 4) ? wl_reg[c * 66 + j] : ((c == 4) ? wl_obj[j] : 0.f); return; }
    u -= 1024;
    if (u < 7168) { int j = u / 112, c = u - j * 112;
        wT_cp[u] = (c < NCLS) ? wl_cls[c * 66 + j] : 0.f; return; }
    u -= 7168;
    if (u < 11312) { int j = u / 112, c = u - j * 112;
        wT_cg[u] = (c < NCLS) ? wg_cls[c * NCLS + j] : 0.f; return; }
    u -= 11312;
    if (u < 128) { bAB[u] = (u & 1) ? bl_c2[u >> 1] : bl_c1[u >> 1]; return; }
    u -= 128;
    if (u < 330) { int cc = u / 66, j = u - cc * 66;
        wro[u] = (cc < 4) ? wl_reg[u] : wl_obj[j]; return; }
    u -= 330;
    if (u < 5) bro[u] = (u < 4) ? bl_reg[u] : bl_obj[0];
}

// ============================================================================
// Node-side GEMM: out[n][c] = sum_j xs(n,j)*wT[j][c] + b[c]
// BNF: fused BN+ReLU on input staging. STOUT: per-block channel sum/sumsq
// partials (shuffle butterfly + plain stores to stpart[blk][128] — NO atomics).
// ============================================================================
template <int COUT, int CPW, int K, int IS, int OS, int MT, bool BNF, bool STOUT>
__global__ __launch_bounds__(256) void gemm_k(const float* __restrict__ in,
                                              const float* __restrict__ wT,
                                              const float* __restrict__ bias,
                                              const float* __restrict__ st,
                                              float* __restrict__ stpart,
                                              float* __restrict__ out) {
    constexpr int CP = 4 * CPW;
    constexpr int RM = MT / 64;
    constexpr int XR = MT + 1;
    __shared__ __align__(16) float xs[K * XR];
    __shared__ __align__(16) float wsh[K * CP];
    int base = blockIdx.x * MT;
    for (int p = threadIdx.x; p < K * CP / 4; p += 256)
        ((float4*)wsh)[p] = ((const float4*)wT)[p];
    for (int p = threadIdx.x; p < MT * K; p += 256) {
        int n = p / K, j = p - n * K;
        float v = (base + n < NN) ? in[(size_t)(base + n) * IS + j] : 0.f;
        if constexpr (BNF) v = fmaxf(fmaf(v, st[128 + j], st[192 + j]), 0.f);
        xs[j * XR + n] = v;
    }
    __syncthreads();
    int wid = __builtin_amdgcn_readfirstlane(threadIdx.x >> 6);
    int lane = threadIdx.x & 63;
    int c0 = wid * CPW;
    if (c0 >= COUT) return;     // after the only barrier -> safe
    float acc[RM][CPW];
#pragma unroll
    for (int k = 0; k < CPW; ++k) {
        float bv = (c0 + k < COUT) ? bias[c0 + k] : 0.f;
#pragma unroll
        for (int r = 0; r < RM; ++r) acc[r][k] = bv;
    }
    for (int j = 0; j < K; ++j) {
        float a[RM];
#pragma unroll
        for (int r = 0; r < RM; ++r) a[r] = xs[j * XR + 64 * r + lane];
#pragma unroll
        for (int q = 0; q < CPW / 4; ++q) {
            float4 wv = *(const float4*)&wsh[j * CP + c0 + 4 * q];
#pragma unroll
            for (int r = 0; r < RM; ++r) {
                acc[r][4 * q + 0] = fmaf(a[r], wv.x, acc[r][4 * q + 0]);
                acc[r][4 * q + 1] = fmaf(a[r], wv.y, acc[r][4 * q + 1]);
                acc[r][4 * q + 2] = fmaf(a[r], wv.z, acc[r][4 * q + 2]);
                acc[r][4 * q + 3] = fmaf(a[r], wv.w, acc[r][4 * q + 3]);
            }
        }
    }
#pragma unroll
    for (int r = 0; r < RM; ++r) {
        int node = base + 64 * r + lane;
        if (node < NN) {
#pragma unroll
            for (int k = 0; k < CPW; ++k)
                if (c0 + k < COUT) out[(size_t)node * OS + c0 + k] = acc[r][k];
        }
    }
    if constexpr (STOUT) {
        float* sp = stpart + (size_t)blockIdx.x * 128;
#pragma unroll
        for (int k = 0; k < CPW; ++k) {
            if (c0 + k < COUT) {
                float s = 0.f, q = 0.f;
#pragma unroll
                for (int r = 0; r < RM; ++r) {
                    float v = (base + 64 * r + lane < NN) ? acc[r][k] : 0.f;
                    s += v;
                    q = fmaf(v, v, q);
                }
#pragma unroll
                for (int off = 1; off < 64; off <<= 1) {
                    s += __shfl_xor(s, off, 64);
                    q += __shfl_xor(q, off, 64);
                }
                if (lane == 0) {
                    sp[c0 + k] = s;
                    sp[64 + c0 + k] = q;
                }
            }
        }
    }
}

// reduce per-block partials -> BN scale/shift. One block, 256 threads.
__global__ __launch_bounds__(256) void bnpar_k(const float* __restrict__ stpart,
                                               const float* __restrict__ g,
                                               const float* __restrict__ b,
                                               float* __restrict__ st) {
    __shared__ float sS[4][64], sQ[4][64];
    int c = threadIdx.x & 63;
    int part = threadIdx.x >> 6;
    float s = 0.f, q = 0.f;
    for (int i = part; i < G128B; i += 4) {
        s += stpart[(size_t)i * 128 + c];
        q += stpart[(size_t)i * 128 + 64 + c];
    }
    sS[part][c] = s;
    sQ[part][c] = q;
    __syncthreads();
    if (part == 0) {
        s = sS[0][c] + sS[1][c] + sS[2][c] + sS[3][c];
        q = sQ[0][c] + sQ[1][c] + sQ[2][c] + sQ[3][c];
        float mu = s * (1.0f / NN);
        float var = q * (1.0f / NN) - mu * mu;
        float sc = g[c] * rsqrtf(var + EPS_BN);
        st[128 + c] = sc;
        st[192 + c] = b[c] - mu * sc;
    }
}

// ============================================================================
// Edge segment-max over CSR. Wave per node, lane = channel. 64-edge batches:
// indices+pos2 loaded coalesced once, broadcast via readlane; 8 gathers in
// flight per unrolled chunk (MLP).
// ============================================================================
__global__ __launch_bounds__(256) void edge1_k(const float* __restrict__ y,   // stride 64
                                               const float2* __restrict__ pos2,
                                               const int* __restrict__ rs,
                                               const int* __restrict__ csrc,
                                               const float* __restrict__ wl,  // (64,66)
                                               float* __restrict__ agg) {
    int wid = __builtin_amdgcn_readfirstlane(threadIdx.x >> 6);
    int lane = threadIdx.x & 63;
    int node = blockIdx.x * 4 + wid;
    if (node >= NN) return;
    float wp0 = wl[lane * 66 + 64], wp1 = wl[lane * 66 + 65];
    float2 pd = pos2[node];
    int i0 = rs[node], i1 = rs[node + 1];
    float acc = NINF;
    for (int ib = i0; ib < i1; ib += 64) {
        int m = i1 - ib;
        if (m > 64) m = 64;
        int t = ib + lane;
        int idx = (t < i1) ? csrc[t] : 0;
        float2 pp = pos2[idx];
        float ppx = pp.x, ppy = pp.y;
        int j = 0;
        for (; j + 8 <= m; j += 8) {
            float v[8];
#pragma unroll
            for (int q = 0; q < 8; ++q)
                v[q] = y[(size_t)rl_i(idx, j + q) * 64 + lane];
#pragma unroll
            for (int q = 0; q < 8; ++q) {
                float dx = rl_f(ppx, j + q) - pd.x, dy = rl_f(ppy, j + q) - pd.y;
                acc = fmaxf(acc, fmaf(dy, wp1, fmaf(dx, wp0, v[q])));
            }
        }
        for (; j + 4 <= m; j += 4) {
            float v[4];
#pragma unroll
            for (int q = 0; q < 4; ++q)
                v[q] = y[(size_t)rl_i(idx, j + q) * 64 + lane];
#pragma unroll
            for (int q = 0; q < 4; ++q) {
                float dx = rl_f(ppx, j + q) - pd.x, dy = rl_f(ppy, j + q) - pd.y;
                acc = fmaxf(acc, fmaf(dy, wp1, fmaf(dx, wp0, v[q])));
            }
        }
        for (; j < m; ++j) {
            int s = rl_i(idx, j);
            float v = y[(size_t)s * 64 + lane];
            acc = fmaxf(acc, fmaf(rl_f(ppy, j) - pd.y, wp1,
                                  fmaf(rl_f(ppx, j) - pd.x, wp0, v)));
        }
    }
    agg[(size_t)node * 64 + lane] = fmaxf(acc, 0.0f);
}

// y12 layout: [n][64]{float2} = (c1 proj, c2 proj)
__global__ __launch_bounds__(256) void edge2_k(const float2* __restrict__ y12,
                                               const float2* __restrict__ pos2,
                                               const int* __restrict__ rs,
                                               const int* __restrict__ csrc,
                                               const float* __restrict__ wlA,
                                               const float* __restrict__ wlB,
                                               float* __restrict__ a1,
                                               float* __restrict__ a2) {
    int wid = __builtin_amdgcn_readfirstlane(threadIdx.x >> 6);
    int lane = threadIdx.x & 63;
    int node = blockIdx.x * 4 + wid;
    if (node >= NN) return;
    float wa0 = wlA[lane * 66 + 64], wa1 = wlA[lane * 66 + 65];
    float wb0 = wlB[lane * 66 + 64], wb1 = wlB[lane * 66 + 65];
    float2 pd = pos2[node];
    int i0 = rs[node], i1 = rs[node + 1];
    float accA = NINF, accB = NINF;
    for (int ib = i0; ib < i1; ib += 64) {
        int m = i1 - ib;
        if (m > 64) m = 64;
        int t = ib + lane;
        int idx = (t < i1) ? csrc[t] : 0;
        float2 pp = pos2[idx];
        float ppx = pp.x, ppy = pp.y;
        int j = 0;
        for (; j + 8 <= m; j += 8) {
            float2 v[8];
#pragma unroll
            for (int q = 0; q < 8; ++q)
                v[q] = y12[(size_t)rl_i(idx, j + q) * 64 + lane];
#pragma unroll
            for (int q = 0; q < 8; ++q) {
                float dx = rl_f(ppx, j + q) - pd.x, dy = rl_f(ppy, j + q) - pd.y;
                accA = fmaxf(accA, fmaf(dy, wa1, fmaf(dx, wa0, v[q].x)));
                accB = fmaxf(accB, fmaf(dy, wb1, fmaf(dx, wb0, v[q].y)));
            }
        }
        for (; j + 4 <= m; j += 4) {
            float2 v[4];
#pragma unroll
            for (int q = 0; q < 4; ++q)
                v[q] = y12[(size_t)rl_i(idx, j + q) * 64 + lane];
#pragma unroll
            for (int q = 0; q < 4; ++q) {
                float dx = rl_f(ppx, j + q) - pd.x, dy = rl_f(ppy, j + q) - pd.y;
                accA = fmaxf(accA, fmaf(dy, wa1, fmaf(dx, wa0, v[q].x)));
                accB = fmaxf(accB, fmaf(dy, wb1, fmaf(dx, wb0, v[q].y)));
            }
        }
        for (; j < m; ++j) {
            float2 v = y12[(size_t)rl_i(idx, j) * 64 + lane];
            float dx = rl_f(ppx, j) - pd.x, dy = rl_f(ppy, j) - pd.y;
            accA = fmaxf(accA, fmaf(dy, wa1, fmaf(dx, wa0, v.x)));
            accB = fmaxf(accB, fmaf(dy, wb1, fmaf(dx, wb0, v.y)));
        }
    }
    a1[(size_t)node * 64 + lane] = fmaxf(accA, 0.0f);
    a2[(size_t)node * 64 + lane] = fmaxf(accB, 0.0f);
}

// cls: wave per node, lane covers channels {lane, lane+64 (clamped)}
__global__ __launch_bounds__(256) void edge_cls_k(const float* __restrict__ y,  // stride 104
                                                  const float2* __restrict__ pos2,
                                                  const int* __restrict__ rs,
                                                  const int* __restrict__ csrc,
                                                  const float* __restrict__ wl,  // (101,66)
                                                  float* __restrict__ agg) {     // stride 104
    int wid = __builtin_amdgcn_readfirstlane(threadIdx.x >> 6);
    int lane = threadIdx.x & 63;
    int node = blockIdx.x * 4 + wid;
    if (node >= NN) return;
    int chi = (lane + 64 < NCLS) ? (lane + 64) : (NCLS - 1);
    float wa0 = wl[lane * 66 + 64], wa1 = wl[lane * 66 + 65];
    float wb0 = wl[chi * 66 + 64], wb1 = wl[chi * 66 + 65];
    float2 pd = pos2[node];
    int i0 = rs[node], i1 = rs[node + 1];
    float accA = NINF, accB = NINF;
    for (int ib = i0; ib < i1; ib += 64) {
        int m = i1 - ib;
        if (m > 64) m = 64;
        int t = ib + lane;
        int idx = (t < i1) ? csrc[t] : 0;
        float2 pp = pos2[idx];
        float ppx = pp.x, ppy = pp.y;
        int j = 0;
        for (; j + 4 <= m; j += 4) {
            float va[4], vb[4];
#pragma unroll
            for (int q = 0; q < 4; ++q) {
                size_t row = (size_t)rl_i(idx, j + q) * 104;
                va[q] = y[row + lane];
                vb[q] = y[row + chi];
            }
#pragma unroll
            for (int q = 0; q < 4; ++q) {
                float dx = rl_f(ppx, j + q) - pd.x, dy = rl_f(ppy, j + q) - pd.y;
                accA = fmaxf(accA, fmaf(dy, wa1, fmaf(dx, wa0, va[q])));
                accB = fmaxf(accB, fmaf(dy, wb1, fmaf(dx, wb0, vb[q])));
            }
        }
        for (; j < m; ++j) {
            size_t row = (size_t)rl_i(idx, j) * 104;
            float va = y[row + lane];
            float vb = y[row + chi];
            float dx = rl_f(ppx, j) - pd.x, dy = rl_f(ppy, j) - pd.y;
            accA = fmaxf(accA, fmaf(dy, wa1, fmaf(dx, wa0, va)));
            accB = fmaxf(accB, fmaf(dy, wb1, fmaf(dx, wb0, vb)));
        }
    }
    agg[(size_t)node * 104 + lane] = fmaxf(accA, 0.0f);
    if (lane + 64 < NCLS) agg[(size_t)node * 104 + 64 + lane] = fmaxf(accB, 0.0f);
}

// reg+obj: 5 channels packed stride 8; wave = 8 edge-slots x 8 channel-slots
__global__ __launch_bounds__(256) void edge_ro_k(const float* __restrict__ y,  // stride 8
                                                 const float2* __restrict__ pos2,
                                                 const int* __restrict__ rs,
                                                 const int* __restrict__ csrc,
                                                 const float* __restrict__ wro,  // (5,66)
                                                 float* __restrict__ aggr,
                                                 float* __restrict__ aggo) {
    int wid = __builtin_amdgcn_readfirstlane(threadIdx.x >> 6);
    int lane = threadIdx.x & 63;
    int node = blockIdx.x * 4 + wid;
    if (node >= NN) return;
    int k = lane >> 3, c = lane & 7;
    int cc = (c < 5) ? c : 4;
    float wp0 = wro[cc * 66 + 64], wp1 = wro[cc * 66 + 65];
    float2 pd = pos2[node];
    int i0 = rs[node], i1 = rs[node + 1];
    float acc = NINF;
    for (int i = i0 + k; i < i1; i += 8) {
        int s = csrc[i];
        float2 p = pos2[s];
        float v = y[(size_t)s * 8 + cc];
        acc = fmaxf(acc, fmaf(p.y - pd.y, wp1, fmaf(p.x - pd.x, wp0, v)));
    }
    acc = fmaxf(acc, __shfl_xor(acc, 8, 64));
    acc = fmaxf(acc, __shfl_xor(acc, 16, 64));
    acc = fmaxf(acc, __shfl_xor(acc, 32, 64));
    acc = fmaxf(acc, 0.0f);
    if (lane < 5) {
        if (lane < 4) aggr[(size_t)node * 4 + lane] = acc;
        else          aggo[node] = acc;
    }
}

__global__ __launch_bounds__(256) void final_ro_k(const float* __restrict__ aggr,
                                                  const float* __restrict__ aggo,
                                                  const float* __restrict__ wgr,
                                                  const float* __restrict__ bgr,
                                                  const float* __restrict__ wgo,
                                                  const float* __restrict__ bgo,
                                                  float* __restrict__ out) {
    int n = blockIdx.x * 256 + threadIdx.x;
    if (n >= NN) return;
    float a0 = aggr[(size_t)n * 4 + 0], a1 = aggr[(size_t)n * 4 + 1];
    float a2 = aggr[(size_t)n * 4 + 2], a3 = aggr[(size_t)n * 4 + 3];
    float* reg = out + (size_t)NN * NCLS;
    float* obj = reg + (size_t)NN * 4;
#pragma unroll
    for (int k = 0; k < 4; ++k) {
        float acc = bgr[k];
        acc = fmaf(a0, wgr[k * 4 + 0], acc);
        acc = fmaf(a1, wgr[k * 4 + 1], acc);
        acc = fmaf(a2, wgr[k * 4 + 2], acc);
        acc = fmaf(a3, wgr[k * 4 + 3], acc);
        reg[(size_t)n * 4 + k] = acc;
    }
    obj[n] = fmaf(aggo[n], wgo[0], bgo[0]);
}

// ============================================================================
extern "C" void kernel_launch(void* const* d_in, const int* in_sizes, int n_in,
                              void* d_out, int out_size, void* d_ws, size_t ws_size,
                              hipStream_t stream) {
    const float* x   = (const float*)d_in[0];
    const float* pos = (const float*)d_in[1];
    const int* ei    = (const int*)d_in[2];
    const int* src = ei;
    const int* dst = ei + NE;
    const float* wl_stem = (const float*)d_in[3];
    const float* bl_stem = (const float*)d_in[4];
    const float* wg_stem = (const float*)d_in[5];
    const float* bg_stem = (const float*)d_in[6];
    const float* g_stem  = (const float*)d_in[7];
    const float* b_stem  = (const float*)d_in[8];
    const float* wl_c1 = (const float*)d_in[9];
    const float* bl_c1 = (const float*)d_in[10];
    const float* wg_c1 = (const float*)d_in[11];
    const float* bg_c1 = (const float*)d_in[12];
    const float* g_c1  = (const float*)d_in[13];
    const float* b_c1  = (const float*)d_in[14];
    const float* wl_c2 = (const float*)d_in[15];
    const float* bl_c2 = (const float*)d_in[16];
    const float* wg_c2 = (const float*)d_in[17];
    const float* bg_c2 = (const float*)d_in[18];
    const float* g_c2  = (const float*)d_in[19];
    const float* b_c2  = (const float*)d_in[20];
    const float* wl_reg = (const float*)d_in[21];
    const float* bl_reg = (const float*)d_in[22];
    const float* wg_reg = (const float*)d_in[23];
    const float* bg_reg = (const float*)d_in[24];
    const float* wl_cls = (const float*)d_in[25];
    const float* bl_cls = (const float*)d_in[26];
    const float* wg_cls = (const float*)d_in[27];
    const float* bg_cls = (const float*)d_in[28];
    const float* wl_obj = (const float*)d_in[29];
    const float* bl_obj = (const float*)d_in[30];
    const float* wg_obj = (const float*)d_in[31];
    const float* bg_obj = (const float*)d_in[32];

    float* ws = (float*)d_ws;
    // Arena: S0[N*128] | S1[N*64] | S2[N*64] | S3[N*64] | ints/smalls
    // bstore (9.6MB) aliases S0 (dead until y12 is written by the c1c2 gemm).
    float* S0 = ws;
    float* S1 = S0 + (size_t)NN * 128;
    float* S2 = S1 + (size_t)NN * 64;
    float* S3 = S2 + (size_t)NN * 64;
    float* y12   = S0;
    float* y_cls = S0;
    float* aggc  = S1;     // N*104 spans S1+S2 (both dead by then)
    int*   bstore = (int*)S0;                     // NBUCK*BCAP ints
    int*   rs   = (int*)(S3 + (size_t)NN * 64);   // NN+1 (padded to 100016)
    int*   csrc = rs + 100016;                    // NE
    float* pos2 = (float*)(csrc + NE);            // NN float2
    float* y_ro = pos2 + (size_t)NN * 2;          // NN*8
    float* aggr = y_ro + (size_t)NN * 8;          // NN*4
    float* aggo = aggr + (size_t)NN * 4;          // NN
    float* st   = aggo + NN;                      // 3*256 (params at [128..255])
    float* st0 = st, *st1 = st + 256, *st2 = st + 512;
    float* wro = st + 768;                        // 336
    float* bro = wro + 336;                       // 8
    int*   bcnt16 = (int*)(bro + 8);              // NBUCK*16 (line-padded)
    int*   bbase  = bcnt16 + NBUCK * 16;          // 256
    float* wT_sp = (float*)(bbase + 256);         // [64][64]
    float* wT_sg = wT_sp + 4096;
    float* wT_12 = wT_sg + 4096;                  // [64][128]
    float* wT_g1 = wT_12 + 8192;
    float* wT_g2 = wT_g1 + 4096;
    float* wT_ro = wT_g2 + 4096;                  // [64][16]
    float* wT_cp = wT_ro + 1024;                  // [64][112]
    float* wT_cg = wT_cp + 7168;                  // [101][112]
    float* bAB   = wT_cg + 11312;                 // 128
    float* stpart = bAB + 128;                    // G128B*128 partials (400 KB)

    hipMemsetAsync(bcnt16, 0, NBUCK * 16 * sizeof(int), stream);

    const int EB = (NE + 255) / 256;      // 6250
    const int NB = (NN + 255) / 256;      // 391
    const int N4 = (NN + 3) / 4;          // 25000
    const int G128 = G128B;               // 782
    const int G64  = (NN + 63) / 64;      // 1563

    // ---- packing + CSR build + pos2 ----
    pack_all_k<<<175, 256, 0, stream>>>(wl_stem, wg_stem, wl_c1, bl_c1, wl_c2,
                                        bl_c2, wg_c1, wg_c2, wl_reg, wl_obj,
                                        bl_reg, bl_obj, wl_cls, wg_cls,
                                        wT_sp, wT_sg, wT_12, wT_g1, wT_g2,
                                        wT_ro, wT_cp, wT_cg, bAB, wro, bro);
    pos2_k<<<NB, 256, 0, stream>>>(pos, (float2*)pos2);
    bucket_k<<<EB, 256, 0, stream>>>(src, dst, bcnt16, bstore);
    bscan_k<<<1, 256, 0, stream>>>(bcnt16, bbase);
    b2csr_k<<<NBUCK, 512, 0, stream>>>(bcnt16, bbase, bstore, rs, csrc);

    // ---- stem ----
    gemm_k<64, 16, 64, 64, 64, 128, false, false><<<G128, 256, 0, stream>>>(
        x, wT_sp, bl_stem, nullptr, nullptr, S1);
    edge1_k<<<N4, 256, 0, stream>>>(S1, (float2*)pos2, rs, csrc, wl_stem, S2);
    gemm_k<64, 16, 64, 64, 64, 128, false, true><<<G128, 256, 0, stream>>>(
        S2, wT_sg, bg_stem, nullptr, stpart, S2);
    bnpar_k<<<1, 256, 0, stream>>>(stpart, g_stem, b_stem, st0);

    // ---- c1 + c2 (BN fused into packed projection, shared edge pass) ----
    gemm_k<128, 32, 64, 64, 128, 128, true, false><<<G128, 256, 0, stream>>>(
        S2, wT_12, bAB, st0, nullptr, y12);
    edge2_k<<<N4, 256, 0, stream>>>((const float2*)y12, (float2*)pos2, rs, csrc,
                                    wl_c1, wl_c2, S1, S3);
    gemm_k<64, 16, 64, 64, 64, 128, false, true><<<G128, 256, 0, stream>>>(
        S1, wT_g1, bg_c1, nullptr, stpart, S1);
    bnpar_k<<<1, 256, 0, stream>>>(stpart, g_c1, b_c1, st1);
    gemm_k<64, 16, 64, 64, 64, 128, false, true><<<G128, 256, 0, stream>>>(
        S3, wT_g2, bg_c2, nullptr, stpart, S3);
    bnpar_k<<<1, 256, 0, stream>>>(stpart, g_c2, b_c2, st2);

    // ---- reg + obj heads (input x1 = BN(S1), fused) ----
    gemm_k<5, 4, 64, 64, 8, 128, true, false><<<G128, 256, 0, stream>>>(
        S1, wT_ro, bro, st1, nullptr, y_ro);
    edge_ro_k<<<N4, 256, 0, stream>>>(y_ro, (float2*)pos2, rs, csrc, wro, aggr, aggo);

    // ---- cls head (input x2 = BN(S3), fused) ----
    gemm_k<101, 28, 64, 64, 104, 128, true, false><<<G128, 256, 0, stream>>>(
        S3, wT_cp, bl_cls, st2, nullptr, y_cls);
    edge_cls_k<<<N4, 256, 0, stream>>>(y_cls, (float2*)pos2, rs, csrc, wl_cls, aggc);
    gemm_k<101, 28, 101, 104, 101, 64, false, false><<<G64, 256, 0, stream>>>(
        aggc, wT_cg, bg_cls, nullptr, nullptr, (float*)d_out);
    final_ro_k<<<NB, 256, 0, stream>>>(aggr, aggo, wg_reg, bg_reg, wg_obj, bg_obj,
                                       (float*)d_out);
}

// Round 9
// 1138.418 us; speedup vs baseline: 1.7595x; 1.1220x over previous
//
#include <hip/hip_runtime.h>

#define NN 100000
#define NE 1600000
#define NCLS 101
#define EPS_BN 1e-5f
#define NINF (-__builtin_inff())
#define NBUCK 196      // ceil(NN/512)
#define BCAP 12288     // max edges/bucket (mean 8163, sd ~90)
#define G128B 782      // ceil(NN/128) gemm blocks (stats partials stride)
#define CHUNK 2048     // edges per binning block

__device__ __forceinline__ int rl_i(int v, int j) {
    return __builtin_amdgcn_readlane(v, j);
}
__device__ __forceinline__ float rl_f(float v, int j) {
    return __int_as_float(__builtin_amdgcn_readlane(__float_as_int(v), j));
}

// ============================================================================
// CSR build, bucketed with block-level binning:
//   bucket_k: per-block LDS sort of a 2048-edge chunk by coarse bucket ->
//             1 global atomic per (block,bucket) -> line-filling global writes
//   bscan_k:  exclusive scan of bucket totals
//   b2csr_k:  per-bucket LDS counting-sort -> rs + csrc
// ============================================================================
__global__ __launch_bounds__(256) void bucket_k(const int* __restrict__ src,
                                                const int* __restrict__ dst,
                                                int* __restrict__ bcnt16,
                                                int* __restrict__ bstore) {
    __shared__ int vals[CHUNK];
    __shared__ int sval[CHUNK];
    __shared__ unsigned char bks[CHUNK];
    __shared__ unsigned char sbk[CHUNK];
    __shared__ int hist[256];
    __shared__ int scn[256];
    __shared__ int loff[256];
    __shared__ int cur[256];
    __shared__ int gshift[256];
    int e0 = blockIdx.x * CHUNK;
    int cnt = NE - e0;
    if (cnt > CHUNK) cnt = CHUNK;
    int t = threadIdx.x;
    hist[t] = 0;
    __syncthreads();
    for (int i = t; i < cnt; i += 256) {
        int d = dst[e0 + i], s = src[e0 + i];
        int b = d >> 9;
        vals[i] = ((d & 511) << 17) | s;
        bks[i] = (unsigned char)b;
        atomicAdd(&hist[b], 1);
    }
    __syncthreads();
    int v = hist[t];
    scn[t] = v;
    __syncthreads();
    for (int off = 1; off < 256; off <<= 1) {
        int u = (t >= off) ? scn[t - off] : 0;
        __syncthreads();
        scn[t] += u;
        __syncthreads();
    }
    loff[t] = scn[t] - v;     // exclusive local offset
    cur[t] = scn[t] - v;
    if (t < NBUCK) {
        int base = (v > 0) ? atomicAdd(&bcnt16[t * 16], v) : 0;
        gshift[t] = base - loff[t];
    }
    __syncthreads();
    for (int i = t; i < cnt; i += 256) {
        int b = bks[i];
        int p = atomicAdd(&cur[b], 1);
        sval[p] = vals[i];
        sbk[p] = (unsigned char)b;
    }
    __syncthreads();
    for (int i = t; i < cnt; i += 256) {
        int b = sbk[i];
        int q = gshift[b] + i;      // position within bucket b's global range
        if (q < BCAP) bstore[(size_t)b * BCAP + q] = sval[i];
    }
}

__global__ __launch_bounds__(256) void bscan_k(const int* __restrict__ bcnt16,
                                               int* __restrict__ bbase) {
    __shared__ int sh[256];
    int t = threadIdx.x;
    int v = (t < NBUCK) ? bcnt16[t * 16] : 0;
    sh[t] = v;
    __syncthreads();
    for (int off = 1; off < 256; off <<= 1) {
        int u = (t >= off) ? sh[t - off] : 0;
        __syncthreads();
        sh[t] += u;
        __syncthreads();
    }
    if (t < NBUCK) bbase[t] = sh[t] - v;   // exclusive
}

__global__ __launch_bounds__(512) void b2csr_k(const int* __restrict__ bcnt16,
                                               const int* __restrict__ bbase,
                                               const int* __restrict__ bstore,
                                               int* __restrict__ rs,
                                               int* __restrict__ csrc) {
    __shared__ int hist[512];
    __shared__ int scn[512];
    __shared__ int cur[512];
    int b = blockIdx.x;
    int t = threadIdx.x;
    int cnt = bcnt16[b * 16];
    if (cnt > BCAP) cnt = BCAP;
    int gbase = bbase[b];
    const int* bs = bstore + (size_t)b * BCAP;
    hist[t] = 0;
    __syncthreads();
    for (int i = t; i < cnt; i += 512) atomicAdd(&hist[bs[i] >> 17], 1);
    __syncthreads();
    int v = hist[t];
    scn[t] = v;
    __syncthreads();
    for (int off = 1; off < 512; off <<= 1) {
        int u = (t >= off) ? scn[t - off] : 0;
        __syncthreads();
        scn[t] += u;
        __syncthreads();
    }
    int ex = scn[t] - v;
    cur[t] = ex;
    int node = b * 512 + t;
    if (node < NN) rs[node] = gbase + ex;
    if (b == 0 && t == 0) rs[NN] = NE;
    __syncthreads();
    for (int i = t; i < cnt; i += 512) {
        int e = bs[i];
        int p = atomicAdd(&cur[e >> 17], 1);
        csrc[gbase + p] = e & 0x1FFFF;
    }
}

__global__ __launch_bounds__(256) void pos2_k(const float* __restrict__ pos,
                                              float2* __restrict__ pos2) {
    int n = blockIdx.x * 256 + threadIdx.x;
    if (n < NN) pos2[n] = make_float2(pos[n * 3], pos[n * 3 + 1]);
}

// ============================================================================
// One-shot weight packing: transpose every GEMM weight into padded [K][CP].
// ============================================================================
__global__ __launch_bounds__(256) void pack_all_k(
    const float* __restrict__ wl_stem, const float* __restrict__ wg_stem,
    const float* __restrict__ wl_c1, const float* __restrict__ bl_c1,
    const float* __restrict__ wl_c2, const float* __restrict__ bl_c2,
    const float* __restrict__ wg_c1, const float* __restrict__ wg_c2,
    const float* __restrict__ wl_reg, const float* __restrict__ wl_obj,
    const float* __restrict__ bl_reg, const float* __restrict__ bl_obj,
    const float* __restrict__ wl_cls, const float* __restrict__ wg_cls,
    float* __restrict__ wT_sp, float* __restrict__ wT_sg,
    float* __restrict__ wT_12, float* __restrict__ wT_g1,
    float* __restrict__ wT_g2, float* __restrict__ wT_ro,
    float* __restrict__ wT_cp, float* __restrict__ wT_cg,
    float* __restrict__ bAB, float* __restrict__ wro, float* __restrict__ bro) {
    int u = blockIdx.x * 256 + threadIdx.x;
    if (u < 4096) { int j = u >> 6, c = u & 63; wT_sp[u] = wl_stem[c * 66 + j]; return; }
    u -= 4096;
    if (u < 4096) { int j = u >> 6, c = u & 63; wT_sg[u] = wg_stem[c * 64 + j]; return; }
    u -= 4096;
    if (u < 8192) { int j = u >> 7, c = u & 127; int k = c >> 1;
        wT_12[u] = ((c & 1) ? wl_c2 : wl_c1)[k * 66 + j]; return; }
    u -= 8192;
    if (u < 4096) { int j = u >> 6, c = u & 63; wT_g1[u] = wg_c1[c * 64 + j]; return; }
    u -= 4096;
    if (u < 4096) { int j = u >> 6, c = u & 63; wT_g2[u] = wg_c2[c * 64 + j]; return; }
    u -= 4096;
    if (u < 1024) { int j = u >> 4, c = u & 15;
        wT_ro[u] = (c < 4) ? wl_reg[c * 66 + j] : ((c == 4) ? wl_obj[j] : 0.f); return; }
    u -= 1024;
    if (u < 7168) { int j = u / 112, c = u - j * 112;
        wT_cp[u] = (c < NCLS) ? wl_cls[c * 66 + j] : 0.f; return; }
    u -= 7168;
    if (u < 11312) { int j = u / 112, c = u - j * 112;
        wT_cg[u] = (c < NCLS) ? wg_cls[c * NCLS + j] : 0.f; return; }
    u -= 11312;
    if (u < 128) { bAB[u] = (u & 1) ? bl_c2[u >> 1] : bl_c1[u >> 1]; return; }
    u -= 128;
    if (u < 330) { int cc = u / 66, j = u - cc * 66;
        wro[u] = (cc < 4) ? wl_reg[u] : wl_obj[j]; return; }
    u -= 330;
    if (u < 5) bro[u] = (u < 4) ? bl_reg[u] : bl_obj[0];
}

// ============================================================================
// Node-side GEMM: out[n][c] = sum_j xs(n,j)*wT[j][c] + b[c]
// BNF: fused BN+ReLU on input staging. STOUT: per-block channel sum/sumsq
// partials (shuffle butterfly + plain stores to stpart[blk][128] — NO atomics).
// ============================================================================
template <int COUT, int CPW, int K, int IS, int OS, int MT, bool BNF, bool STOUT>
__global__ __launch_bounds__(256) void gemm_k(const float* __restrict__ in,
                                              const float* __restrict__ wT,
                                              const float* __restrict__ bias,
                                              const float* __restrict__ st,
                                              float* __restrict__ stpart,
                                              float* __restrict__ out) {
    constexpr int CP = 4 * CPW;
    constexpr int RM = MT / 64;
    constexpr int XR = MT + 1;
    __shared__ __align__(16) float xs[K * XR];
    __shared__ __align__(16) float wsh[K * CP];
    int base = blockIdx.x * MT;
    for (int p = threadIdx.x; p < K * CP / 4; p += 256)
        ((float4*)wsh)[p] = ((const float4*)wT)[p];
    for (int p = threadIdx.x; p < MT * K; p += 256) {
        int n = p / K, j = p - n * K;
        float v = (base + n < NN) ? in[(size_t)(base + n) * IS + j] : 0.f;
        if constexpr (BNF) v = fmaxf(fmaf(v, st[128 + j], st[192 + j]), 0.f);
        xs[j * XR + n] = v;
    }
    __syncthreads();
    int wid = __builtin_amdgcn_readfirstlane(threadIdx.x >> 6);
    int lane = threadIdx.x & 63;
    int c0 = wid * CPW;
    if (c0 >= COUT) return;     // after the only barrier -> safe
    float acc[RM][CPW];
#pragma unroll
    for (int k = 0; k < CPW; ++k) {
        float bv = (c0 + k < COUT) ? bias[c0 + k] : 0.f;
#pragma unroll
        for (int r = 0; r < RM; ++r) acc[r][k] = bv;
    }
    for (int j = 0; j < K; ++j) {
        float a[RM];
#pragma unroll
        for (int r = 0; r < RM; ++r) a[r] = xs[j * XR + 64 * r + lane];
#pragma unroll
        for (int q = 0; q < CPW / 4; ++q) {
            float4 wv = *(const float4*)&wsh[j * CP + c0 + 4 * q];
#pragma unroll
            for (int r = 0; r < RM; ++r) {
                acc[r][4 * q + 0] = fmaf(a[r], wv.x, acc[r][4 * q + 0]);
                acc[r][4 * q + 1] = fmaf(a[r], wv.y, acc[r][4 * q + 1]);
                acc[r][4 * q + 2] = fmaf(a[r], wv.z, acc[r][4 * q + 2]);
                acc[r][4 * q + 3] = fmaf(a[r], wv.w, acc[r][4 * q + 3]);
            }
        }
    }
#pragma unroll
    for (int r = 0; r < RM; ++r) {
        int node = base + 64 * r + lane;
        if (node < NN) {
#pragma unroll
            for (int k = 0; k < CPW; ++k)
                if (c0 + k < COUT) out[(size_t)node * OS + c0 + k] = acc[r][k];
        }
    }
    if constexpr (STOUT) {
        float* sp = stpart + (size_t)blockIdx.x * 128;
#pragma unroll
        for (int k = 0; k < CPW; ++k) {
            if (c0 + k < COUT) {
                float s = 0.f, q = 0.f;
#pragma unroll
                for (int r = 0; r < RM; ++r) {
                    float v = (base + 64 * r + lane < NN) ? acc[r][k] : 0.f;
                    s += v;
                    q = fmaf(v, v, q);
                }
#pragma unroll
                for (int off = 1; off < 64; off <<= 1) {
                    s += __shfl_xor(s, off, 64);
                    q += __shfl_xor(q, off, 64);
                }
                if (lane == 0) {
                    sp[c0 + k] = s;
                    sp[64 + c0 + k] = q;
                }
            }
        }
    }
}

// reduce per-block partials -> BN scale/shift. One block, 256 threads.
__global__ __launch_bounds__(256) void bnpar_k(const float* __restrict__ stpart,
                                               const float* __restrict__ g,
                                               const float* __restrict__ b,
                                               float* __restrict__ st) {
    __shared__ float sS[4][64], sQ[4][64];
    int c = threadIdx.x & 63;
    int part = threadIdx.x >> 6;
    float s = 0.f, q = 0.f;
    for (int i = part; i < G128B; i += 4) {
        s += stpart[(size_t)i * 128 + c];
        q += stpart[(size_t)i * 128 + 64 + c];
    }
    sS[part][c] = s;
    sQ[part][c] = q;
    __syncthreads();
    if (part == 0) {
        s = sS[0][c] + sS[1][c] + sS[2][c] + sS[3][c];
        q = sQ[0][c] + sQ[1][c] + sQ[2][c] + sQ[3][c];
        float mu = s * (1.0f / NN);
        float var = q * (1.0f / NN) - mu * mu;
        float sc = g[c] * rsqrtf(var + EPS_BN);
        st[128 + c] = sc;
        st[192 + c] = b[c] - mu * sc;
    }
}

// ============================================================================
// Edge segment-max over CSR. Wave per node, lane = channel. 64-edge batches:
// indices+pos2 loaded coalesced once, broadcast via readlane; 8 gathers in
// flight per unrolled chunk (MLP).
// ============================================================================
__global__ __launch_bounds__(256) void edge1_k(const float* __restrict__ y,   // stride 64
                                               const float2* __restrict__ pos2,
                                               const int* __restrict__ rs,
                                               const int* __restrict__ csrc,
                                               const float* __restrict__ wl,  // (64,66)
                                               float* __restrict__ agg) {
    int wid = __builtin_amdgcn_readfirstlane(threadIdx.x >> 6);
    int lane = threadIdx.x & 63;
    int node = blockIdx.x * 4 + wid;
    if (node >= NN) return;
    float wp0 = wl[lane * 66 + 64], wp1 = wl[lane * 66 + 65];
    float2 pd = pos2[node];
    int i0 = rs[node], i1 = rs[node + 1];
    float acc = NINF;
    for (int ib = i0; ib < i1; ib += 64) {
        int m = i1 - ib;
        if (m > 64) m = 64;
        int t = ib + lane;
        int idx = (t < i1) ? csrc[t] : 0;
        float2 pp = pos2[idx];
        float ppx = pp.x, ppy = pp.y;
        int j = 0;
        for (; j + 8 <= m; j += 8) {
            float v[8];
#pragma unroll
            for (int q = 0; q < 8; ++q)
                v[q] = y[(size_t)rl_i(idx, j + q) * 64 + lane];
#pragma unroll
            for (int q = 0; q < 8; ++q) {
                float dx = rl_f(ppx, j + q) - pd.x, dy = rl_f(ppy, j + q) - pd.y;
                acc = fmaxf(acc, fmaf(dy, wp1, fmaf(dx, wp0, v[q])));
            }
        }
        for (; j + 4 <= m; j += 4) {
            float v[4];
#pragma unroll
            for (int q = 0; q < 4; ++q)
                v[q] = y[(size_t)rl_i(idx, j + q) * 64 + lane];
#pragma unroll
            for (int q = 0; q < 4; ++q) {
                float dx = rl_f(ppx, j + q) - pd.x, dy = rl_f(ppy, j + q) - pd.y;
                acc = fmaxf(acc, fmaf(dy, wp1, fmaf(dx, wp0, v[q])));
            }
        }
        for (; j < m; ++j) {
            int s = rl_i(idx, j);
            float v = y[(size_t)s * 64 + lane];
            acc = fmaxf(acc, fmaf(rl_f(ppy, j) - pd.y, wp1,
                                  fmaf(rl_f(ppx, j) - pd.x, wp0, v)));
        }
    }
    agg[(size_t)node * 64 + lane] = fmaxf(acc, 0.0f);
}

// y12 layout: [n][64]{float2} = (c1 proj, c2 proj)
__global__ __launch_bounds__(256) void edge2_k(const float2* __restrict__ y12,
                                               const float2* __restrict__ pos2,
                                               const int* __restrict__ rs,
                                               const int* __restrict__ csrc,
                                               const float* __restrict__ wlA,
                                               const float* __restrict__ wlB,
                                               float* __restrict__ a1,
                                               float* __restrict__ a2) {
    int wid = __builtin_amdgcn_readfirstlane(threadIdx.x >> 6);
    int lane = threadIdx.x & 63;
    int node = blockIdx.x * 4 + wid;
    if (node >= NN) return;
    float wa0 = wlA[lane * 66 + 64], wa1 = wlA[lane * 66 + 65];
    float wb0 = wlB[lane * 66 + 64], wb1 = wlB[lane * 66 + 65];
    float2 pd = pos2[node];
    int i0 = rs[node], i1 = rs[node + 1];
    float accA = NINF, accB = NINF;
    for (int ib = i0; ib < i1; ib += 64) {
        int m = i1 - ib;
        if (m > 64) m = 64;
        int t = ib + lane;
        int idx = (t < i1) ? csrc[t] : 0;
        float2 pp = pos2[idx];
        float ppx = pp.x, ppy = pp.y;
        int j = 0;
        for (; j + 8 <= m; j += 8) {
            float2 v[8];
#pragma unroll
            for (int q = 0; q < 8; ++q)
                v[q] = y12[(size_t)rl_i(idx, j + q) * 64 + lane];
#pragma unroll
            for (int q = 0; q < 8; ++q) {
                float dx = rl_f(ppx, j + q) - pd.x, dy = rl_f(ppy, j + q) - pd.y;
                accA = fmaxf(accA, fmaf(dy, wa1, fmaf(dx, wa0, v[q].x)));
                accB = fmaxf(accB, fmaf(dy, wb1, fmaf(dx, wb0, v[q].y)));
            }
        }
        for (; j + 4 <= m; j += 4) {
            float2 v[4];
#pragma unroll
            for (int q = 0; q < 4; ++q)
                v[q] = y12[(size_t)rl_i(idx, j + q) * 64 + lane];
#pragma unroll
            for (int q = 0; q < 4; ++q) {
                float dx = rl_f(ppx, j + q) - pd.x, dy = rl_f(ppy, j + q) - pd.y;
                accA = fmaxf(accA, fmaf(dy, wa1, fmaf(dx, wa0, v[q].x)));
                accB = fmaxf(accB, fmaf(dy, wb1, fmaf(dx, wb0, v[q].y)));
            }
        }
        for (; j < m; ++j) {
            float2 v = y12[(size_t)rl_i(idx, j) * 64 + lane];
            float dx = rl_f(ppx, j) - pd.x, dy = rl_f(ppy, j) - pd.y;
            accA = fmaxf(accA, fmaf(dy, wa1, fmaf(dx, wa0, v.x)));
            accB = fmaxf(accB, fmaf(dy, wb1, fmaf(dx, wb0, v.y)));
        }
    }
    a1[(size_t)node * 64 + lane] = fmaxf(accA, 0.0f);
    a2[(size_t)node * 64 + lane] = fmaxf(accB, 0.0f);
}

// cls: wave per node, lane covers channels {lane, lane+64 (clamped)}
__global__ __launch_bounds__(256) void edge_cls_k(const float* __restrict__ y,  // stride 104
                                                  const float2* __restrict__ pos2,
                                                  const int* __restrict__ rs,
                                                  const int* __restrict__ csrc,
                                                  const float* __restrict__ wl,  // (101,66)
                                                  float* __restrict__ agg) {     // stride 104
    int wid = __builtin_amdgcn_readfirstlane(threadIdx.x >> 6);
    int lane = threadIdx.x & 63;
    int node = blockIdx.x * 4 + wid;
    if (node >= NN) return;
    int chi = (lane + 64 < NCLS) ? (lane + 64) : (NCLS - 1);
    float wa0 = wl[lane * 66 + 64], wa1 = wl[lane * 66 + 65];
    float wb0 = wl[chi * 66 + 64], wb1 = wl[chi * 66 + 65];
    float2 pd = pos2[node];
    int i0 = rs[node], i1 = rs[node + 1];
    float accA = NINF, accB = NINF;
    for (int ib = i0; ib < i1; ib += 64) {
        int m = i1 - ib;
        if (m > 64) m = 64;
        int t = ib + lane;
        int idx = (t < i1) ? csrc[t] : 0;
        float2 pp = pos2[idx];
        float ppx = pp.x, ppy = pp.y;
        int j = 0;
        for (; j + 4 <= m; j += 4) {
            float va[4], vb[4];
#pragma unroll
            for (int q = 0; q < 4; ++q) {
                size_t row = (size_t)rl_i(idx, j + q) * 104;
                va[q] = y[row + lane];
                vb[q] = y[row + chi];
            }
#pragma unroll
            for (int q = 0; q < 4; ++q) {
                float dx = rl_f(ppx, j + q) - pd.x, dy = rl_f(ppy, j + q) - pd.y;
                accA = fmaxf(accA, fmaf(dy, wa1, fmaf(dx, wa0, va[q])));
                accB = fmaxf(accB, fmaf(dy, wb1, fmaf(dx, wb0, vb[q])));
            }
        }
        for (; j < m; ++j) {
            size_t row = (size_t)rl_i(idx, j) * 104;
            float va = y[row + lane];
            float vb = y[row + chi];
            float dx = rl_f(ppx, j) - pd.x, dy = rl_f(ppy, j) - pd.y;
            accA = fmaxf(accA, fmaf(dy, wa1, fmaf(dx, wa0, va)));
            accB = fmaxf(accB, fmaf(dy, wb1, fmaf(dx, wb0, vb)));
        }
    }
    agg[(size_t)node * 104 + lane] = fmaxf(accA, 0.0f);
    if (lane + 64 < NCLS) agg[(size_t)node * 104 + 64 + lane] = fmaxf(accB, 0.0f);
}

// reg+obj: 5 channels packed stride 8; wave = 8 edge-slots x 8 channel-slots
__global__ __launch_bounds__(256) void edge_ro_k(const float* __restrict__ y,  // stride 8
                                                 const float2* __restrict__ pos2,
                                                 const int* __restrict__ rs,
                                                 const int* __restrict__ csrc,
                                                 const float* __restrict__ wro,  // (5,66)
                                                 float* __restrict__ aggr,
                                                 float* __restrict__ aggo) {
    int wid = __builtin_amdgcn_readfirstlane(threadIdx.x >> 6);
    int lane = threadIdx.x & 63;
    int node = blockIdx.x * 4 + wid;
    if (node >= NN) return;
    int k = lane >> 3, c = lane & 7;
    int cc = (c < 5) ? c : 4;
    float wp0 = wro[cc * 66 + 64], wp1 = wro[cc * 66 + 65];
    float2 pd = pos2[node];
    int i0 = rs[node], i1 = rs[node + 1];
    float acc = NINF;
    for (int i = i0 + k; i < i1; i += 8) {
        int s = csrc[i];
        float2 p = pos2[s];
        float v = y[(size_t)s * 8 + cc];
        acc = fmaxf(acc, fmaf(p.y - pd.y, wp1, fmaf(p.x - pd.x, wp0, v)));
    }
    acc = fmaxf(acc, __shfl_xor(acc, 8, 64));
    acc = fmaxf(acc, __shfl_xor(acc, 16, 64));
    acc = fmaxf(acc, __shfl_xor(acc, 32, 64));
    acc = fmaxf(acc, 0.0f);
    if (lane < 5) {
        if (lane < 4) aggr[(size_t)node * 4 + lane] = acc;
        else          aggo[node] = acc;
    }
}

__global__ __launch_bounds__(256) void final_ro_k(const float* __restrict__ aggr,
                                                  const float* __restrict__ aggo,
                                                  const float* __restrict__ wgr,
                                                  const float* __restrict__ bgr,
                                                  const float* __restrict__ wgo,
                                                  const float* __restrict__ bgo,
                                                  float* __restrict__ out) {
    int n = blockIdx.x * 256 + threadIdx.x;
    if (n >= NN) return;
    float a0 = aggr[(size_t)n * 4 + 0], a1 = aggr[(size_t)n * 4 + 1];
    float a2 = aggr[(size_t)n * 4 + 2], a3 = aggr[(size_t)n * 4 + 3];
    float* reg = out + (size_t)NN * NCLS;
    float* obj = reg + (size_t)NN * 4;
#pragma unroll
    for (int k = 0; k < 4; ++k) {
        float acc = bgr[k];
        acc = fmaf(a0, wgr[k * 4 + 0], acc);
        acc = fmaf(a1, wgr[k * 4 + 1], acc);
        acc = fmaf(a2, wgr[k * 4 + 2], acc);
        acc = fmaf(a3, wgr[k * 4 + 3], acc);
        reg[(size_t)n * 4 + k] = acc;
    }
    obj[n] = fmaf(aggo[n], wgo[0], bgo[0]);
}

// ============================================================================
extern "C" void kernel_launch(void* const* d_in, const int* in_sizes, int n_in,
                              void* d_out, int out_size, void* d_ws, size_t ws_size,
                              hipStream_t stream) {
    const float* x   = (const float*)d_in[0];
    const float* pos = (const float*)d_in[1];
    const int* ei    = (const int*)d_in[2];
    const int* src = ei;
    const int* dst = ei + NE;
    const float* wl_stem = (const float*)d_in[3];
    const float* bl_stem = (const float*)d_in[4];
    const float* wg_stem = (const float*)d_in[5];
    const float* bg_stem = (const float*)d_in[6];
    const float* g_stem  = (const float*)d_in[7];
    const float* b_stem  = (const float*)d_in[8];
    const float* wl_c1 = (const float*)d_in[9];
    const float* bl_c1 = (const float*)d_in[10];
    const float* wg_c1 = (const float*)d_in[11];
    const float* bg_c1 = (const float*)d_in[12];
    const float* g_c1  = (const float*)d_in[13];
    const float* b_c1  = (const float*)d_in[14];
    const float* wl_c2 = (const float*)d_in[15];
    const float* bl_c2 = (const float*)d_in[16];
    const float* wg_c2 = (const float*)d_in[17];
    const float* bg_c2 = (const float*)d_in[18];
    const float* g_c2  = (const float*)d_in[19];
    const float* b_c2  = (const float*)d_in[20];
    const float* wl_reg = (const float*)d_in[21];
    const float* bl_reg = (const float*)d_in[22];
    const float* wg_reg = (const float*)d_in[23];
    const float* bg_reg = (const float*)d_in[24];
    const float* wl_cls = (const float*)d_in[25];
    const float* bl_cls = (const float*)d_in[26];
    const float* wg_cls = (const float*)d_in[27];
    const float* bg_cls = (const float*)d_in[28];
    const float* wl_obj = (const float*)d_in[29];
    const float* bl_obj = (const float*)d_in[30];
    const float* wg_obj = (const float*)d_in[31];
    const float* bg_obj = (const float*)d_in[32];

    float* ws = (float*)d_ws;
    // Arena: S0[N*128] | S1[N*64] | S2[N*64] | S3[N*64] | ints/smalls
    // bstore (9.6MB) aliases S0 (dead until y12 is written by the c1c2 gemm).
    float* S0 = ws;
    float* S1 = S0 + (size_t)NN * 128;
    float* S2 = S1 + (size_t)NN * 64;
    float* S3 = S2 + (size_t)NN * 64;
    float* y12   = S0;
    float* y_cls = S0;
    float* aggc  = S1;     // N*104 spans S1+S2 (both dead by then)
    int*   bstore = (int*)S0;                     // NBUCK*BCAP ints
    int*   rs   = (int*)(S3 + (size_t)NN * 64);   // NN+1 (padded to 100016)
    int*   csrc = rs + 100016;                    // NE
    float* pos2 = (float*)(csrc + NE);            // NN float2
    float* y_ro = pos2 + (size_t)NN * 2;          // NN*8
    float* aggr = y_ro + (size_t)NN * 8;          // NN*4
    float* aggo = aggr + (size_t)NN * 4;          // NN
    float* st   = aggo + NN;                      // 3*256 (params at [128..255])
    float* st0 = st, *st1 = st + 256, *st2 = st + 512;
    float* wro = st + 768;                        // 336
    float* bro = wro + 336;                       // 8
    int*   bcnt16 = (int*)(bro + 8);              // NBUCK*16 (line-padded)
    int*   bbase  = bcnt16 + NBUCK * 16;          // 256
    float* wT_sp = (float*)(bbase + 256);         // [64][64]
    float* wT_sg = wT_sp + 4096;
    float* wT_12 = wT_sg + 4096;                  // [64][128]
    float* wT_g1 = wT_12 + 8192;
    float* wT_g2 = wT_g1 + 4096;
    float* wT_ro = wT_g2 + 4096;                  // [64][16]
    float* wT_cp = wT_ro + 1024;                  // [64][112]
    float* wT_cg = wT_cp + 7168;                  // [101][112]
    float* bAB   = wT_cg + 11312;                 // 128
    float* stpart = bAB + 128;                    // G128B*128 partials (400 KB)

    hipMemsetAsync(bcnt16, 0, NBUCK * 16 * sizeof(int), stream);

    const int NB = (NN + 255) / 256;      // 391
    const int N4 = (NN + 3) / 4;          // 25000
    const int G128 = G128B;               // 782
    const int G64  = (NN + 63) / 64;      // 1563
    const int CB = (NE + CHUNK - 1) / CHUNK;  // 782 binning blocks

    // ---- packing + CSR build + pos2 ----
    pack_all_k<<<175, 256, 0, stream>>>(wl_stem, wg_stem, wl_c1, bl_c1, wl_c2,
                                        bl_c2, wg_c1, wg_c2, wl_reg, wl_obj,
                                        bl_reg, bl_obj, wl_cls, wg_cls,
                                        wT_sp, wT_sg, wT_12, wT_g1, wT_g2,
                                        wT_ro, wT_cp, wT_cg, bAB, wro, bro);
    pos2_k<<<NB, 256, 0, stream>>>(pos, (float2*)pos2);
    bucket_k<<<CB, 256, 0, stream>>>(src, dst, bcnt16, bstore);
    bscan_k<<<1, 256, 0, stream>>>(bcnt16, bbase);
    b2csr_k<<<NBUCK, 512, 0, stream>>>(bcnt16, bbase, bstore, rs, csrc);

    // ---- stem ----
    gemm_k<64, 16, 64, 64, 64, 128, false, false><<<G128, 256, 0, stream>>>(
        x, wT_sp, bl_stem, nullptr, nullptr, S1);
    edge1_k<<<N4, 256, 0, stream>>>(S1, (float2*)pos2, rs, csrc, wl_stem, S2);
    gemm_k<64, 16, 64, 64, 64, 128, false, true><<<G128, 256, 0, stream>>>(
        S2, wT_sg, bg_stem, nullptr, stpart, S2);
    bnpar_k<<<1, 256, 0, stream>>>(stpart, g_stem, b_stem, st0);

    // ---- c1 + c2 (BN fused into packed projection, shared edge pass) ----
    gemm_k<128, 32, 64, 64, 128, 128, true, false><<<G128, 256, 0, stream>>>(
        S2, wT_12, bAB, st0, nullptr, y12);
    edge2_k<<<N4, 256, 0, stream>>>((const float2*)y12, (float2*)pos2, rs, csrc,
                                    wl_c1, wl_c2, S1, S3);
    gemm_k<64, 16, 64, 64, 64, 128, false, true><<<G128, 256, 0, stream>>>(
        S1, wT_g1, bg_c1, nullptr, stpart, S1);
    bnpar_k<<<1, 256, 0, stream>>>(stpart, g_c1, b_c1, st1);
    gemm_k<64, 16, 64, 64, 64, 128, false, true><<<G128, 256, 0, stream>>>(
        S3, wT_g2, bg_c2, nullptr, stpart, S3);
    bnpar_k<<<1, 256, 0, stream>>>(stpart, g_c2, b_c2, st2);

    // ---- reg + obj heads (input x1 = BN(S1), fused) ----
    gemm_k<5, 4, 64, 64, 8, 128, true, false><<<G128, 256, 0, stream>>>(
        S1, wT_ro, bro, st1, nullptr, y_ro);
    edge_ro_k<<<N4, 256, 0, stream>>>(y_ro, (float2*)pos2, rs, csrc, wro, aggr, aggo);

    // ---- cls head (input x2 = BN(S3), fused) ----
    gemm_k<101, 28, 64, 64, 104, 128, true, false><<<G128, 256, 0, stream>>>(
        S3, wT_cp, bl_cls, st2, nullptr, y_cls);
    edge_cls_k<<<N4, 256, 0, stream>>>(y_cls, (float2*)pos2, rs, csrc, wl_cls, aggc);
    gemm_k<101, 28, 101, 104, 101, 64, false, false><<<G64, 256, 0, stream>>>(
        aggc, wT_cg, bg_cls, nullptr, nullptr, (float*)d_out);
    final_ro_k<<<NB, 256, 0, stream>>>(aggr, aggo, wg_reg, bg_reg, wg_obj, bg_obj,
                                       (float*)d_out);
}

// Round 10
// 1011.000 us; speedup vs baseline: 1.9812x; 1.1260x over previous
//
#include <hip/hip_runtime.h>
#include <hip/hip_bf16.h>

#define NN 100000
#define NE 1600000
#define NCLS 101
#define EPS_BN 1e-5f
#define NINF (-__builtin_inff())
#define NBUCK 196      // ceil(NN/512)
#define BCAP 12288     // max edges/bucket (mean 8163, sd ~90)
#define G128B 782      // ceil(NN/128) gemm blocks (stats partials stride)
#define CHUNK 2048     // edges per binning block

__device__ __forceinline__ int rl_i(int v, int j) {
    return __builtin_amdgcn_readlane(v, j);
}
__device__ __forceinline__ float rl_f(float v, int j) {
    return __int_as_float(__builtin_amdgcn_readlane(__float_as_int(v), j));
}
__device__ __forceinline__ float b2f(unsigned short u) {
    return __uint_as_float(((unsigned)u) << 16);
}

// ============================================================================
// CSR build, bucketed with block-level binning (R9, unchanged).
// ============================================================================
__global__ __launch_bounds__(256) void bucket_k(const int* __restrict__ src,
                                                const int* __restrict__ dst,
                                                int* __restrict__ bcnt16,
                                                int* __restrict__ bstore) {
    __shared__ int vals[CHUNK];
    __shared__ int sval[CHUNK];
    __shared__ unsigned char bks[CHUNK];
    __shared__ unsigned char sbk[CHUNK];
    __shared__ int hist[256];
    __shared__ int scn[256];
    __shared__ int loff[256];
    __shared__ int cur[256];
    __shared__ int gshift[256];
    int e0 = blockIdx.x * CHUNK;
    int cnt = NE - e0;
    if (cnt > CHUNK) cnt = CHUNK;
    int t = threadIdx.x;
    hist[t] = 0;
    __syncthreads();
    for (int i = t; i < cnt; i += 256) {
        int d = dst[e0 + i], s = src[e0 + i];
        int b = d >> 9;
        vals[i] = ((d & 511) << 17) | s;
        bks[i] = (unsigned char)b;
        atomicAdd(&hist[b], 1);
    }
    __syncthreads();
    int v = hist[t];
    scn[t] = v;
    __syncthreads();
    for (int off = 1; off < 256; off <<= 1) {
        int u = (t >= off) ? scn[t - off] : 0;
        __syncthreads();
        scn[t] += u;
        __syncthreads();
    }
    loff[t] = scn[t] - v;
    cur[t] = scn[t] - v;
    if (t < NBUCK) {
        int base = (v > 0) ? atomicAdd(&bcnt16[t * 16], v) : 0;
        gshift[t] = base - loff[t];
    }
    __syncthreads();
    for (int i = t; i < cnt; i += 256) {
        int b = bks[i];
        int p = atomicAdd(&cur[b], 1);
        sval[p] = vals[i];
        sbk[p] = (unsigned char)b;
    }
    __syncthreads();
    for (int i = t; i < cnt; i += 256) {
        int b = sbk[i];
        int q = gshift[b] + i;
        if (q < BCAP) bstore[(size_t)b * BCAP + q] = sval[i];
    }
}

__global__ __launch_bounds__(256) void bscan_k(const int* __restrict__ bcnt16,
                                               int* __restrict__ bbase) {
    __shared__ int sh[256];
    int t = threadIdx.x;
    int v = (t < NBUCK) ? bcnt16[t * 16] : 0;
    sh[t] = v;
    __syncthreads();
    for (int off = 1; off < 256; off <<= 1) {
        int u = (t >= off) ? sh[t - off] : 0;
        __syncthreads();
        sh[t] += u;
        __syncthreads();
    }
    if (t < NBUCK) bbase[t] = sh[t] - v;
}

__global__ __launch_bounds__(512) void b2csr_k(const int* __restrict__ bcnt16,
                                               const int* __restrict__ bbase,
                                               const int* __restrict__ bstore,
                                               int* __restrict__ rs,
                                               int* __restrict__ csrc) {
    __shared__ int hist[512];
    __shared__ int scn[512];
    __shared__ int cur[512];
    int b = blockIdx.x;
    int t = threadIdx.x;
    int cnt = bcnt16[b * 16];
    if (cnt > BCAP) cnt = BCAP;
    int gbase = bbase[b];
    const int* bs = bstore + (size_t)b * BCAP;
    hist[t] = 0;
    __syncthreads();
    for (int i = t; i < cnt; i += 512) atomicAdd(&hist[bs[i] >> 17], 1);
    __syncthreads();
    int v = hist[t];
    scn[t] = v;
    __syncthreads();
    for (int off = 1; off < 512; off <<= 1) {
        int u = (t >= off) ? scn[t - off] : 0;
        __syncthreads();
        scn[t] += u;
        __syncthreads();
    }
    int ex = scn[t] - v;
    cur[t] = ex;
    int node = b * 512 + t;
    if (node < NN) rs[node] = gbase + ex;
    if (b == 0 && t == 0) rs[NN] = NE;
    __syncthreads();
    for (int i = t; i < cnt; i += 512) {
        int e = bs[i];
        int p = atomicAdd(&cur[e >> 17], 1);
        csrc[gbase + p] = e & 0x1FFFF;
    }
}

__global__ __launch_bounds__(256) void pos2_k(const float* __restrict__ pos,
                                              float2* __restrict__ pos2) {
    int n = blockIdx.x * 256 + threadIdx.x;
    if (n < NN) pos2[n] = make_float2(pos[n * 3], pos[n * 3 + 1]);
}

// ============================================================================
// One-shot weight packing (unchanged).
// ============================================================================
__global__ __launch_bounds__(256) void pack_all_k(
    const float* __restrict__ wl_stem, const float* __restrict__ wg_stem,
    const float* __restrict__ wl_c1, const float* __restrict__ bl_c1,
    const float* __restrict__ wl_c2, const float* __restrict__ bl_c2,
    const float* __restrict__ wg_c1, const float* __restrict__ wg_c2,
    const float* __restrict__ wl_reg, const float* __restrict__ wl_obj,
    const float* __restrict__ bl_reg, const float* __restrict__ bl_obj,
    const float* __restrict__ wl_cls, const float* __restrict__ wg_cls,
    float* __restrict__ wT_sp, float* __restrict__ wT_sg,
    float* __restrict__ wT_12, float* __restrict__ wT_g1,
    float* __restrict__ wT_g2, float* __restrict__ wT_ro,
    float* __restrict__ wT_cp, float* __restrict__ wT_cg,
    float* __restrict__ bAB, float* __restrict__ wro, float* __restrict__ bro) {
    int u = blockIdx.x * 256 + threadIdx.x;
    if (u < 4096) { int j = u >> 6, c = u & 63; wT_sp[u] = wl_stem[c * 66 + j]; return; }
    u -= 4096;
    if (u < 4096) { int j = u >> 6, c = u & 63; wT_sg[u] = wg_stem[c * 64 + j]; return; }
    u -= 4096;
    if (u < 8192) { int j = u >> 7, c = u & 127; int k = c >> 1;
        wT_12[u] = ((c & 1) ? wl_c2 : wl_c1)[k * 66 + j]; return; }
    u -= 8192;
    if (u < 4096) { int j = u >> 6, c = u & 63; wT_g1[u] = wg_c1[c * 64 + j]; return; }
    u -= 4096;
    if (u < 4096) { int j = u >> 6, c = u & 63; wT_g2[u] = wg_c2[c * 64 + j]; return; }
    u -= 4096;
    if (u < 1024) { int j = u >> 4, c = u & 15;
        wT_ro[u] = (c < 4) ? wl_reg[c * 66 + j] : ((c == 4) ? wl_obj[j] : 0.f); return; }
    u -= 1024;
    if (u < 7168) { int j = u / 112, c = u - j * 112;
        wT_cp[u] = (c < NCLS) ? wl_cls[c * 66 + j] : 0.f; return; }
    u -= 7168;
    if (u < 11312) { int j = u / 112, c = u - j * 112;
        wT_cg[u] = (c < NCLS) ? wg_cls[c * NCLS + j] : 0.f; return; }
    u -= 11312;
    if (u < 128) { bAB[u] = (u & 1) ? bl_c2[u >> 1] : bl_c1[u >> 1]; return; }
    u -= 128;
    if (u < 330) { int cc = u / 66, j = u - cc * 66;
        wro[u] = (cc < 4) ? wl_reg[u] : wl_obj[j]; return; }
    u -= 330;
    if (u < 5) bro[u] = (u < 4) ? bl_reg[u] : bl_obj[0];
}

// ============================================================================
// Node-side GEMM. BNF: fused BN+ReLU on input staging. STOUT: per-block
// sum/sumsq partials (no atomics). BOUT: write output as bf16 (RN) — used for
// the projection tensors that only feed the edge gather passes.
// ============================================================================
template <int COUT, int CPW, int K, int IS, int OS, int MT, bool BNF, bool STOUT,
          bool BOUT>
__global__ __launch_bounds__(256) void gemm_k(const float* __restrict__ in,
                                              const float* __restrict__ wT,
                                              const float* __restrict__ bias,
                                              const float* __restrict__ st,
                                              float* __restrict__ stpart,
                                              float* __restrict__ out) {
    constexpr int CP = 4 * CPW;
    constexpr int RM = MT / 64;
    constexpr int XR = MT + 1;
    __shared__ __align__(16) float xs[K * XR];
    __shared__ __align__(16) float wsh[K * CP];
    int base = blockIdx.x * MT;
    for (int p = threadIdx.x; p < K * CP / 4; p += 256)
        ((float4*)wsh)[p] = ((const float4*)wT)[p];
    for (int p = threadIdx.x; p < MT * K; p += 256) {
        int n = p / K, j = p - n * K;
        float v = (base + n < NN) ? in[(size_t)(base + n) * IS + j] : 0.f;
        if constexpr (BNF) v = fmaxf(fmaf(v, st[128 + j], st[192 + j]), 0.f);
        xs[j * XR + n] = v;
    }
    __syncthreads();
    int wid = __builtin_amdgcn_readfirstlane(threadIdx.x >> 6);
    int lane = threadIdx.x & 63;
    int c0 = wid * CPW;
    if (c0 >= COUT) return;     // after the only barrier -> safe
    float acc[RM][CPW];
#pragma unroll
    for (int k = 0; k < CPW; ++k) {
        float bv = (c0 + k < COUT) ? bias[c0 + k] : 0.f;
#pragma unroll
        for (int r = 0; r < RM; ++r) acc[r][k] = bv;
    }
    for (int j = 0; j < K; ++j) {
        float a[RM];
#pragma unroll
        for (int r = 0; r < RM; ++r) a[r] = xs[j * XR + 64 * r + lane];
#pragma unroll
        for (int q = 0; q < CPW / 4; ++q) {
            float4 wv = *(const float4*)&wsh[j * CP + c0 + 4 * q];
#pragma unroll
            for (int r = 0; r < RM; ++r) {
                acc[r][4 * q + 0] = fmaf(a[r], wv.x, acc[r][4 * q + 0]);
                acc[r][4 * q + 1] = fmaf(a[r], wv.y, acc[r][4 * q + 1]);
                acc[r][4 * q + 2] = fmaf(a[r], wv.z, acc[r][4 * q + 2]);
                acc[r][4 * q + 3] = fmaf(a[r], wv.w, acc[r][4 * q + 3]);
            }
        }
    }
#pragma unroll
    for (int r = 0; r < RM; ++r) {
        int node = base + 64 * r + lane;
        if (node < NN) {
#pragma unroll
            for (int k = 0; k < CPW; ++k) {
                if (c0 + k < COUT) {
                    if constexpr (BOUT) {
                        __hip_bfloat16* ob = (__hip_bfloat16*)out;
                        ob[(size_t)node * OS + c0 + k] = __float2bfloat16(acc[r][k]);
                    } else {
                        out[(size_t)node * OS + c0 + k] = acc[r][k];
                    }
                }
            }
        }
    }
    if constexpr (STOUT) {
        float* sp = stpart + (size_t)blockIdx.x * 128;
#pragma unroll
        for (int k = 0; k < CPW; ++k) {
            if (c0 + k < COUT) {
                float s = 0.f, q = 0.f;
#pragma unroll
                for (int r = 0; r < RM; ++r) {
                    float v = (base + 64 * r + lane < NN) ? acc[r][k] : 0.f;
                    s += v;
                    q = fmaf(v, v, q);
                }
#pragma unroll
                for (int off = 1; off < 64; off <<= 1) {
                    s += __shfl_xor(s, off, 64);
                    q += __shfl_xor(q, off, 64);
                }
                if (lane == 0) {
                    sp[c0 + k] = s;
                    sp[64 + c0 + k] = q;
                }
            }
        }
    }
}

// reduce per-block partials -> BN scale/shift. One block, 256 threads.
__global__ __launch_bounds__(256) void bnpar_k(const float* __restrict__ stpart,
                                               const float* __restrict__ g,
                                               const float* __restrict__ b,
                                               float* __restrict__ st) {
    __shared__ float sS[4][64], sQ[4][64];
    int c = threadIdx.x & 63;
    int part = threadIdx.x >> 6;
    float s = 0.f, q = 0.f;
    for (int i = part; i < G128B; i += 4) {
        s += stpart[(size_t)i * 128 + c];
        q += stpart[(size_t)i * 128 + 64 + c];
    }
    sS[part][c] = s;
    sQ[part][c] = q;
    __syncthreads();
    if (part == 0) {
        s = sS[0][c] + sS[1][c] + sS[2][c] + sS[3][c];
        q = sQ[0][c] + sQ[1][c] + sQ[2][c] + sQ[3][c];
        float mu = s * (1.0f / NN);
        float var = q * (1.0f / NN) - mu * mu;
        float sc = g[c] * rsqrtf(var + EPS_BN);
        st[128 + c] = sc;
        st[192 + c] = b[c] - mu * sc;
    }
}

// ============================================================================
// Edge segment-max over CSR, bf16 payloads. Wave per node, lane = channel.
// 64-edge batches: indices+pos2 loaded coalesced, broadcast via readlane;
// 8 gathers in flight per unrolled chunk.
// ============================================================================
__global__ __launch_bounds__(256) void edge1_k(const unsigned short* __restrict__ y,  // bf16, stride 64
                                               const float2* __restrict__ pos2,
                                               const int* __restrict__ rs,
                                               const int* __restrict__ csrc,
                                               const float* __restrict__ wl,  // (64,66)
                                               float* __restrict__ agg) {
    int wid = __builtin_amdgcn_readfirstlane(threadIdx.x >> 6);
    int lane = threadIdx.x & 63;
    int node = blockIdx.x * 4 + wid;
    if (node >= NN) return;
    float wp0 = wl[lane * 66 + 64], wp1 = wl[lane * 66 + 65];
    float2 pd = pos2[node];
    int i0 = rs[node], i1 = rs[node + 1];
    float acc = NINF;
    for (int ib = i0; ib < i1; ib += 64) {
        int m = i1 - ib;
        if (m > 64) m = 64;
        int t = ib + lane;
        int idx = (t < i1) ? csrc[t] : 0;
        float2 pp = pos2[idx];
        float ppx = pp.x, ppy = pp.y;
        int j = 0;
        for (; j + 8 <= m; j += 8) {
            float v[8];
#pragma unroll
            for (int q = 0; q < 8; ++q)
                v[q] = b2f(y[(size_t)rl_i(idx, j + q) * 64 + lane]);
#pragma unroll
            for (int q = 0; q < 8; ++q) {
                float dx = rl_f(ppx, j + q) - pd.x, dy = rl_f(ppy, j + q) - pd.y;
                acc = fmaxf(acc, fmaf(dy, wp1, fmaf(dx, wp0, v[q])));
            }
        }
        for (; j < m; ++j) {
            float v = b2f(y[(size_t)rl_i(idx, j) * 64 + lane]);
            acc = fmaxf(acc, fmaf(rl_f(ppy, j) - pd.y, wp1,
                                  fmaf(rl_f(ppx, j) - pd.x, wp0, v)));
        }
    }
    agg[(size_t)node * 64 + lane] = fmaxf(acc, 0.0f);
}

// y12: bf16 [n][64]{c1,c2} pairs -> one uint per lane
__global__ __launch_bounds__(256) void edge2_k(const unsigned* __restrict__ y12,
                                               const float2* __restrict__ pos2,
                                               const int* __restrict__ rs,
                                               const int* __restrict__ csrc,
                                               const float* __restrict__ wlA,
                                               const float* __restrict__ wlB,
                                               float* __restrict__ a1,
                                               float* __restrict__ a2) {
    int wid = __builtin_amdgcn_readfirstlane(threadIdx.x >> 6);
    int lane = threadIdx.x & 63;
    int node = blockIdx.x * 4 + wid;
    if (node >= NN) return;
    float wa0 = wlA[lane * 66 + 64], wa1 = wlA[lane * 66 + 65];
    float wb0 = wlB[lane * 66 + 64], wb1 = wlB[lane * 66 + 65];
    float2 pd = pos2[node];
    int i0 = rs[node], i1 = rs[node + 1];
    float accA = NINF, accB = NINF;
    for (int ib = i0; ib < i1; ib += 64) {
        int m = i1 - ib;
        if (m > 64) m = 64;
        int t = ib + lane;
        int idx = (t < i1) ? csrc[t] : 0;
        float2 pp = pos2[idx];
        float ppx = pp.x, ppy = pp.y;
        int j = 0;
        for (; j + 8 <= m; j += 8) {
            unsigned w[8];
#pragma unroll
            for (int q = 0; q < 8; ++q)
                w[q] = y12[(size_t)rl_i(idx, j + q) * 64 + lane];
#pragma unroll
            for (int q = 0; q < 8; ++q) {
                float dx = rl_f(ppx, j + q) - pd.x, dy = rl_f(ppy, j + q) - pd.y;
                accA = fmaxf(accA, fmaf(dy, wa1, fmaf(dx, wa0,
                                        b2f((unsigned short)w[q]))));
                accB = fmaxf(accB, fmaf(dy, wb1, fmaf(dx, wb0,
                                        b2f((unsigned short)(w[q] >> 16)))));
            }
        }
        for (; j < m; ++j) {
            unsigned w = y12[(size_t)rl_i(idx, j) * 64 + lane];
            float dx = rl_f(ppx, j) - pd.x, dy = rl_f(ppy, j) - pd.y;
            accA = fmaxf(accA, fmaf(dy, wa1, fmaf(dx, wa0, b2f((unsigned short)w))));
            accB = fmaxf(accB, fmaf(dy, wb1, fmaf(dx, wb0,
                                    b2f((unsigned short)(w >> 16)))));
        }
    }
    a1[(size_t)node * 64 + lane] = fmaxf(accA, 0.0f);
    a2[(size_t)node * 64 + lane] = fmaxf(accB, 0.0f);
}

// cls: wave per node, lane covers channels {lane, lane+64 (clamped)}
__global__ __launch_bounds__(256) void edge_cls_k(const unsigned short* __restrict__ y,  // bf16, stride 104
                                                  const float2* __restrict__ pos2,
                                                  const int* __restrict__ rs,
                                                  const int* __restrict__ csrc,
                                                  const float* __restrict__ wl,  // (101,66)
                                                  float* __restrict__ agg) {     // fp32, stride 104
    int wid = __builtin_amdgcn_readfirstlane(threadIdx.x >> 6);
    int lane = threadIdx.x & 63;
    int node = blockIdx.x * 4 + wid;
    if (node >= NN) return;
    int chi = (lane + 64 < NCLS) ? (lane + 64) : (NCLS - 1);
    float wa0 = wl[lane * 66 + 64], wa1 = wl[lane * 66 + 65];
    float wb0 = wl[chi * 66 + 64], wb1 = wl[chi * 66 + 65];
    float2 pd = pos2[node];
    int i0 = rs[node], i1 = rs[node + 1];
    float accA = NINF, accB = NINF;
    for (int ib = i0; ib < i1; ib += 64) {
        int m = i1 - ib;
        if (m > 64) m = 64;
        int t = ib + lane;
        int idx = (t < i1) ? csrc[t] : 0;
        float2 pp = pos2[idx];
        float ppx = pp.x, ppy = pp.y;
        int j = 0;
        for (; j + 4 <= m; j += 4) {
            float va[4], vb[4];
#pragma unroll
            for (int q = 0; q < 4; ++q) {
                size_t row = (size_t)rl_i(idx, j + q) * 104;
                va[q] = b2f(y[row + lane]);
                vb[q] = b2f(y[row + chi]);
            }
#pragma unroll
            for (int q = 0; q < 4; ++q) {
                float dx = rl_f(ppx, j + q) - pd.x, dy = rl_f(ppy, j + q) - pd.y;
                accA = fmaxf(accA, fmaf(dy, wa1, fmaf(dx, wa0, va[q])));
                accB = fmaxf(accB, fmaf(dy, wb1, fmaf(dx, wb0, vb[q])));
            }
        }
        for (; j < m; ++j) {
            size_t row = (size_t)rl_i(idx, j) * 104;
            float va = b2f(y[row + lane]);
            float vb = b2f(y[row + chi]);
            float dx = rl_f(ppx, j) - pd.x, dy = rl_f(ppy, j) - pd.y;
            accA = fmaxf(accA, fmaf(dy, wa1, fmaf(dx, wa0, va)));
            accB = fmaxf(accB, fmaf(dy, wb1, fmaf(dx, wb0, vb)));
        }
    }
    agg[(size_t)node * 104 + lane] = fmaxf(accA, 0.0f);
    if (lane + 64 < NCLS) agg[(size_t)node * 104 + 64 + lane] = fmaxf(accB, 0.0f);
}

// reg+obj: 5 bf16 channels packed stride 8; wave = 8 edge-slots x 8 ch-slots
__global__ __launch_bounds__(256) void edge_ro_k(const unsigned short* __restrict__ y,  // bf16, stride 8
                                                 const float2* __restrict__ pos2,
                                                 const int* __restrict__ rs,
                                                 const int* __restrict__ csrc,
                                                 const float* __restrict__ wro,  // (5,66)
                                                 float* __restrict__ aggr,
                                                 float* __restrict__ aggo) {
    int wid = __builtin_amdgcn_readfirstlane(threadIdx.x >> 6);
    int lane = threadIdx.x & 63;
    int node = blockIdx.x * 4 + wid;
    if (node >= NN) return;
    int k = lane >> 3, c = lane & 7;
    int cc = (c < 5) ? c : 4;
    float wp0 = wro[cc * 66 + 64], wp1 = wro[cc * 66 + 65];
    float2 pd = pos2[node];
    int i0 = rs[node], i1 = rs[node + 1];
    float acc = NINF;
    for (int i = i0 + k; i < i1; i += 8) {
        int s = csrc[i];
        float2 p = pos2[s];
        float v = b2f(y[(size_t)s * 8 + cc]);
        acc = fmaxf(acc, fmaf(p.y - pd.y, wp1, fmaf(p.x - pd.x, wp0, v)));
    }
    acc = fmaxf(acc, __shfl_xor(acc, 8, 64));
    acc = fmaxf(acc, __shfl_xor(acc, 16, 64));
    acc = fmaxf(acc, __shfl_xor(acc, 32, 64));
    acc = fmaxf(acc, 0.0f);
    if (lane < 5) {
        if (lane < 4) aggr[(size_t)node * 4 + lane] = acc;
        else          aggo[node] = acc;
    }
}

__global__ __launch_bounds__(256) void final_ro_k(const float* __restrict__ aggr,
                                                  const float* __restrict__ aggo,
                                                  const float* __restrict__ wgr,
                                                  const float* __restrict__ bgr,
                                                  const float* __restrict__ wgo,
                                                  const float* __restrict__ bgo,
                                                  float* __restrict__ out) {
    int n = blockIdx.x * 256 + threadIdx.x;
    if (n >= NN) return;
    float a0 = aggr[(size_t)n * 4 + 0], a1 = aggr[(size_t)n * 4 + 1];
    float a2 = aggr[(size_t)n * 4 + 2], a3 = aggr[(size_t)n * 4 + 3];
    float* reg = out + (size_t)NN * NCLS;
    float* obj = reg + (size_t)NN * 4;
#pragma unroll
    for (int k = 0; k < 4; ++k) {
        float acc = bgr[k];
        acc = fmaf(a0, wgr[k * 4 + 0], acc);
        acc = fmaf(a1, wgr[k * 4 + 1], acc);
        acc = fmaf(a2, wgr[k * 4 + 2], acc);
        acc = fmaf(a3, wgr[k * 4 + 3], acc);
        reg[(size_t)n * 4 + k] = acc;
    }
    obj[n] = fmaf(aggo[n], wgo[0], bgo[0]);
}

// ============================================================================
extern "C" void kernel_launch(void* const* d_in, const int* in_sizes, int n_in,
                              void* d_out, int out_size, void* d_ws, size_t ws_size,
                              hipStream_t stream) {
    const float* x   = (const float*)d_in[0];
    const float* pos = (const float*)d_in[1];
    const int* ei    = (const int*)d_in[2];
    const int* src = ei;
    const int* dst = ei + NE;
    const float* wl_stem = (const float*)d_in[3];
    const float* bl_stem = (const float*)d_in[4];
    const float* wg_stem = (const float*)d_in[5];
    const float* bg_stem = (const float*)d_in[6];
    const float* g_stem  = (const float*)d_in[7];
    const float* b_stem  = (const float*)d_in[8];
    const float* wl_c1 = (const float*)d_in[9];
    const float* bl_c1 = (const float*)d_in[10];
    const float* wg_c1 = (const float*)d_in[11];
    const float* bg_c1 = (const float*)d_in[12];
    const float* g_c1  = (const float*)d_in[13];
    const float* b_c1  = (const float*)d_in[14];
    const float* wl_c2 = (const float*)d_in[15];
    const float* bl_c2 = (const float*)d_in[16];
    const float* wg_c2 = (const float*)d_in[17];
    const float* bg_c2 = (const float*)d_in[18];
    const float* g_c2  = (const float*)d_in[19];
    const float* b_c2  = (const float*)d_in[20];
    const float* wl_reg = (const float*)d_in[21];
    const float* bl_reg = (const float*)d_in[22];
    const float* wg_reg = (const float*)d_in[23];
    const float* bg_reg = (const float*)d_in[24];
    const float* wl_cls = (const float*)d_in[25];
    const float* bl_cls = (const float*)d_in[26];
    const float* wg_cls = (const float*)d_in[27];
    const float* bg_cls = (const float*)d_in[28];
    const float* wl_obj = (const float*)d_in[29];
    const float* bl_obj = (const float*)d_in[30];
    const float* wg_obj = (const float*)d_in[31];
    const float* bg_obj = (const float*)d_in[32];

    float* ws = (float*)d_ws;
    // Arena: S0[N*128] | S1[N*64] | S2[N*64] | S3[N*64] | ints/smalls
    // bf16 projections reuse the fp32 slots (half-occupied). bstore aliases S0.
    float* S0 = ws;
    float* S1 = S0 + (size_t)NN * 128;
    float* S2 = S1 + (size_t)NN * 64;
    float* S3 = S2 + (size_t)NN * 64;
    float* y12   = S0;       // bf16 [n][128]
    float* y_cls = S0;       // bf16 [n][104]
    float* aggc  = S1;       // fp32 N*104 spans S1+S2 (both dead by then)
    int*   bstore = (int*)S0;                     // NBUCK*BCAP ints
    int*   rs   = (int*)(S3 + (size_t)NN * 64);   // NN+1 (padded to 100016)
    int*   csrc = rs + 100016;                    // NE
    float* pos2 = (float*)(csrc + NE);            // NN float2
    float* y_ro = pos2 + (size_t)NN * 2;          // bf16 [n][8] (slot sized for fp32)
    float* aggr = y_ro + (size_t)NN * 8;          // NN*4
    float* aggo = aggr + (size_t)NN * 4;          // NN
    float* st   = aggo + NN;                      // 3*256 (params at [128..255])
    float* st0 = st, *st1 = st + 256, *st2 = st + 512;
    float* wro = st + 768;                        // 336
    float* bro = wro + 336;                       // 8
    int*   bcnt16 = (int*)(bro + 8);              // NBUCK*16 (line-padded)
    int*   bbase  = bcnt16 + NBUCK * 16;          // 256
    float* wT_sp = (float*)(bbase + 256);         // [64][64]
    float* wT_sg = wT_sp + 4096;
    float* wT_12 = wT_sg + 4096;                  // [64][128]
    float* wT_g1 = wT_12 + 8192;
    float* wT_g2 = wT_g1 + 4096;
    float* wT_ro = wT_g2 + 4096;                  // [64][16]
    float* wT_cp = wT_ro + 1024;                  // [64][112]
    float* wT_cg = wT_cp + 7168;                  // [101][112]
    float* bAB   = wT_cg + 11312;                 // 128
    float* stpart = bAB + 128;                    // G128B*128 partials (400 KB)

    hipMemsetAsync(bcnt16, 0, NBUCK * 16 * sizeof(int), stream);

    const int NB = (NN + 255) / 256;      // 391
    const int N4 = (NN + 3) / 4;          // 25000
    const int G128 = G128B;               // 782
    const int G64  = (NN + 63) / 64;      // 1563
    const int CB = (NE + CHUNK - 1) / CHUNK;  // 782 binning blocks

    // ---- packing + CSR build + pos2 ----
    pack_all_k<<<175, 256, 0, stream>>>(wl_stem, wg_stem, wl_c1, bl_c1, wl_c2,
                                        bl_c2, wg_c1, wg_c2, wl_reg, wl_obj,
                                        bl_reg, bl_obj, wl_cls, wg_cls,
                                        wT_sp, wT_sg, wT_12, wT_g1, wT_g2,
                                        wT_ro, wT_cp, wT_cg, bAB, wro, bro);
    pos2_k<<<NB, 256, 0, stream>>>(pos, (float2*)pos2);
    bucket_k<<<CB, 256, 0, stream>>>(src, dst, bcnt16, bstore);
    bscan_k<<<1, 256, 0, stream>>>(bcnt16, bbase);
    b2csr_k<<<NBUCK, 512, 0, stream>>>(bcnt16, bbase, bstore, rs, csrc);

    // ---- stem ----
    gemm_k<64, 16, 64, 64, 64, 128, false, false, true><<<G128, 256, 0, stream>>>(
        x, wT_sp, bl_stem, nullptr, nullptr, S1);          // y_stem bf16 in S1
    edge1_k<<<N4, 256, 0, stream>>>((const unsigned short*)S1, (float2*)pos2, rs,
                                    csrc, wl_stem, S2);
    gemm_k<64, 16, 64, 64, 64, 128, false, true, false><<<G128, 256, 0, stream>>>(
        S2, wT_sg, bg_stem, nullptr, stpart, S2);
    bnpar_k<<<1, 256, 0, stream>>>(stpart, g_stem, b_stem, st0);

    // ---- c1 + c2 (BN fused into packed projection, shared edge pass) ----
    gemm_k<128, 32, 64, 64, 128, 128, true, false, true><<<G128, 256, 0, stream>>>(
        S2, wT_12, bAB, st0, nullptr, y12);                // y12 bf16
    edge2_k<<<N4, 256, 0, stream>>>((const unsigned*)y12, (float2*)pos2, rs, csrc,
                                    wl_c1, wl_c2, S1, S3);
    gemm_k<64, 16, 64, 64, 64, 128, false, true, false><<<G128, 256, 0, stream>>>(
        S1, wT_g1, bg_c1, nullptr, stpart, S1);
    bnpar_k<<<1, 256, 0, stream>>>(stpart, g_c1, b_c1, st1);
    gemm_k<64, 16, 64, 64, 64, 128, false, true, false><<<G128, 256, 0, stream>>>(
        S3, wT_g2, bg_c2, nullptr, stpart, S3);
    bnpar_k<<<1, 256, 0, stream>>>(stpart, g_c2, b_c2, st2);

    // ---- reg + obj heads (input x1 = BN(S1), fused) ----
    gemm_k<5, 4, 64, 64, 8, 128, true, false, true><<<G128, 256, 0, stream>>>(
        S1, wT_ro, bro, st1, nullptr, y_ro);               // y_ro bf16
    edge_ro_k<<<N4, 256, 0, stream>>>((const unsigned short*)y_ro, (float2*)pos2,
                                      rs, csrc, wro, aggr, aggo);

    // ---- cls head (input x2 = BN(S3), fused) ----
    gemm_k<101, 28, 64, 64, 104, 128, true, false, true><<<G128, 256, 0, stream>>>(
        S3, wT_cp, bl_cls, st2, nullptr, y_cls);           // y_cls bf16
    edge_cls_k<<<N4, 256, 0, stream>>>((const unsigned short*)y_cls, (float2*)pos2,
                                       rs, csrc, wl_cls, aggc);
    gemm_k<101, 28, 101, 104, 101, 64, false, false, false><<<G64, 256, 0, stream>>>(
        aggc, wT_cg, bg_cls, nullptr, nullptr, (float*)d_out);
    final_ro_k<<<NB, 256, 0, stream>>>(aggr, aggo, wg_reg, bg_reg, wg_obj, bg_obj,
                                       (float*)d_out);
}